// Round 3
// baseline (665.613 us; speedup 1.0000x reference)
//
#include <hip/hip_runtime.h>
#include <hip/hip_bf16.h>

// B=4, S=2048, D=1024, DH=64. Inputs/outputs are FLOAT32 (per reference).
typedef short bf16x8 __attribute__((ext_vector_type(8)));
typedef float f32x4  __attribute__((ext_vector_type(4)));
typedef _Float16 f16x4 __attribute__((ext_vector_type(4)));

#define MFMA16(a,b,c) __builtin_amdgcn_mfma_f32_16x16x32_bf16((a),(b),(c),0,0,0)

__device__ __forceinline__ short f2bf(float f){
  union { float f; unsigned u; } v; v.f = f;
  unsigned r = v.u + 0x7fffu + ((v.u >> 16) & 1u);
  return (short)(r >> 16);
}
__device__ __forceinline__ float bf2f(short h){
  union { unsigned u; float f; } v; v.u = ((unsigned)(unsigned short)h) << 16;
  return v.f;
}
// 8 consecutive fp32 -> hi/lo bf16 fragments
__device__ __forceinline__ void split8(const float* __restrict__ p, bf16x8& h, bf16x8& l){
  f32x4 a = *(const f32x4*)p;
  f32x4 b = *(const f32x4*)(p + 4);
  float t[8] = {a[0],a[1],a[2],a[3],b[0],b[1],b[2],b[3]};
  #pragma unroll
  for (int e = 0; e < 8; ++e){
    short hs = f2bf(t[e]);
    h[e] = hs;
    l[e] = f2bf(t[e] - bf2f(hs));
  }
}

// ---------------- P0: transpose+split 6 weights (1024x64 f32 -> 64x1024 bf16 hi/lo) ----------------
__global__ void k_wt(const float* w0, const float* w1, const float* w2,
                     const float* w3, const float* w4, const float* w5,
                     unsigned short* __restrict__ wth, unsigned short* __restrict__ wtl){
  int p = blockIdx.y;
  const float* wp = p==0?w0:p==1?w1:p==2?w2:p==3?w3:p==4?w4:w5;
  int idx = blockIdx.x*256 + threadIdx.x;     // [0,65536)
  int n = idx >> 10, k = idx & 1023;
  float v = wp[k*64 + n];
  short hs = f2bf(v);
  wth[(size_t)p*65536 + n*1024 + k] = (unsigned short)hs;
  wtl[(size_t)p*65536 + n*1024 + k] = (unsigned short)f2bf(v - bf2f(hs));
}

// ---------------- P1: projections x(8192x1024 f32)@w -> proj f32 (8192x64) x6, split MFMA ----------------
__global__ __launch_bounds__(256) void k_proj(const float* __restrict__ x,
                                              const unsigned short* __restrict__ wth,
                                              const unsigned short* __restrict__ wtl,
                                              float* __restrict__ proj){
  int p = blockIdx.y;
  int m_base = blockIdx.x * 64;
  int w = threadIdx.x >> 6, lane = threadIdx.x & 63;
  int lm = lane & 15, quad = lane >> 4;
  const unsigned short* wthp = wth + (size_t)p*65536;
  const unsigned short* wtlp = wtl + (size_t)p*65536;
  f32x4 acc[4] = {};
  int row = m_base + w*16 + lm;
  const float* xrow = x + (size_t)row*1024 + quad*8;
  size_t boff = (size_t)lm*1024 + quad*8;
  for (int k0 = 0; k0 < 1024; k0 += 32){
    bf16x8 ah, al;
    split8(xrow + k0, ah, al);
    #pragma unroll
    for (int t = 0; t < 4; ++t){
      bf16x8 bh = *(const bf16x8*)(wthp + boff + t*16384 + k0);
      bf16x8 bl = *(const bf16x8*)(wtlp + boff + t*16384 + k0);
      acc[t] = MFMA16(ah, bh, acc[t]);
      acc[t] = MFMA16(ah, bl, acc[t]);
      acc[t] = MFMA16(al, bh, acc[t]);
    }
  }
  float* op = proj + (size_t)p*524288;
  #pragma unroll
  for (int t = 0; t < 4; ++t){
    #pragma unroll
    for (int e = 0; e < 4; ++e){
      int r = m_base + w*16 + quad*4 + e;
      op[(size_t)r*64 + t*16 + lm] = acc[t][e];
    }
  }
}

// ---------------- P1b: V_c f32 -> V_c^T bf16 hi/lo (per batch 64 x 2048) ----------------
__global__ void k_vct(const float* __restrict__ proj,
                      unsigned short* __restrict__ vcth, unsigned short* __restrict__ vctl){
  int b = blockIdx.y;
  int idx = blockIdx.x*256 + threadIdx.x;     // [0,131072)
  int d = idx >> 11, s = idx & 2047;
  const float* vc = proj + 5*524288 + (size_t)b*131072;
  float v = vc[(size_t)s*64 + d];
  short hs = f2bf(v);
  vcth[(size_t)b*131072 + (size_t)d*2048 + s] = (unsigned short)hs;
  vctl[(size_t)b*131072 + (size_t)d*2048 + s] = (unsigned short)f2bf(v - bf2f(hs));
}

// ---------------- P2: term1 (causal, scaled) and sigmoid gate, hi/lo bf16 ----------------
template<bool TERM1>
__device__ __forceinline__ void p2_compute_store(const float* __restrict__ A, const float* __restrict__ Bm,
                 unsigned short* __restrict__ oh, unsigned short* __restrict__ ol,
                 int a128, int b128, int w, int lm, int quad){
  f32x4 acc[8][2] = {};
  #pragma unroll
  for (int ks = 0; ks < 2; ++ks){
    bf16x8 bh[2], bl[2];
    #pragma unroll
    for (int n = 0; n < 2; ++n){
      int col = b128*128 + w*32 + n*16 + lm;
      split8(Bm + (size_t)col*64 + ks*32 + quad*8, bh[n], bl[n]);
    }
    #pragma unroll
    for (int m = 0; m < 8; ++m){
      int row = a128*128 + m*16 + lm;
      bf16x8 ah, al;
      split8(A + (size_t)row*64 + ks*32 + quad*8, ah, al);
      #pragma unroll
      for (int n = 0; n < 2; ++n){
        acc[m][n] = MFMA16(ah, bh[n], acc[m][n]);
        acc[m][n] = MFMA16(ah, bl[n], acc[m][n]);
        acc[m][n] = MFMA16(al, bh[n], acc[m][n]);
      }
    }
  }
  #pragma unroll
  for (int m = 0; m < 8; ++m){
    int r64 = (a128*128 + m*16) >> 6;
    #pragma unroll
    for (int n = 0; n < 2; ++n){
      int j64 = (b128*128 + w*32 + n*16) >> 6;
      bool wr = TERM1 ? (j64 <= r64 + 1) : (j64 >= r64 - 1);
      if (wr){
        #pragma unroll
        for (int e = 0; e < 4; ++e){
          int irow = a128*128 + m*16 + quad*4 + e;
          int jcol = b128*128 + w*32 + n*16 + lm;
          float v = acc[m][n][e] * 0.125f;
          float outv;
          if (TERM1) outv = (jcol <= irow) ? v : 0.0f;
          else       outv = (jcol >  irow) ? (1.0f/(1.0f + __expf(-v))) : 0.0f;
          short hs = f2bf(outv);
          float lo = outv - bf2f(hs);
          size_t idx = (size_t)irow*2048 + jcol;
          oh[idx] = (unsigned short)hs;
          ol[idx] = (unsigned short)f2bf(lo);
        }
      }
    }
  }
}

__global__ __launch_bounds__(256) void k_p2(const float* __restrict__ proj,
    unsigned short* __restrict__ t1h, unsigned short* __restrict__ t1l,
    unsigned short* __restrict__ sgh, unsigned short* __restrict__ sgl){
  int b = blockIdx.y;
  int a128 = blockIdx.x >> 4, b128 = blockIdx.x & 15;
  int w = threadIdx.x >> 6, lane = threadIdx.x & 63;
  int lm = lane & 15, quad = lane >> 4;
  const float* Qu = proj + 0*524288 + (size_t)b*131072;
  const float* Ku = proj + 1*524288 + (size_t)b*131072;
  const float* Vu = proj + 2*524288 + (size_t)b*131072;
  const float* Qc = proj + 3*524288 + (size_t)b*131072;
  size_t mat = (size_t)b * 4194304u;
  if (b128 <= a128 + 1)
    p2_compute_store<true >(Qc, Vu, t1h + mat, t1l + mat, a128, b128, w, lm, quad);
  if (b128 >= a128 - 1)
    p2_compute_store<false>(Qu, Ku, sgh + mat, sgl + mat, a128, b128, w, lm, quad);
}

// ---------------- P3: S_u = term1 @ sig^T (split, tri-tiled) + fused S_c, logits(fp16) out ----------------
__global__ __launch_bounds__(256) void k_p3(const float* __restrict__ proj,
    const unsigned short* __restrict__ t1h, const unsigned short* __restrict__ t1l,
    const unsigned short* __restrict__ sgh, const unsigned short* __restrict__ sgl,
    _Float16* __restrict__ lg){
  int b = blockIdx.y;
  int t = blockIdx.x;
  int I = (int)((sqrtf(8.0f*(float)t + 1.0f) - 1.0f)*0.5f);
  while ((I+1)*(I+2)/2 <= t) ++I;
  while (I*(I+1)/2 > t) --I;
  int K = t - I*(I+1)/2;                      // K <= I, 128-granular tri tile
  int tid = threadIdx.x, w = tid >> 6, lane = tid & 63;
  int lm = lane & 15, quad = lane >> 4;
  size_t mat = (size_t)b * 4194304u;
  const unsigned short* t1hb = t1h + mat;
  const unsigned short* t1lb = t1l + mat;
  const unsigned short* sghb = sgh + mat;
  const unsigned short* sglb = sgl + mat;

  f32x4 su[8][2] = {};
  for (int j64 = 2*K; j64 <= 2*I + 1; ++j64){
    bf16x8 bh[2][2], bl[2][2];                // [ks][n]
    #pragma unroll
    for (int ks = 0; ks < 2; ++ks){
      #pragma unroll
      for (int n = 0; n < 2; ++n){
        size_t off = (size_t)(K*128 + w*32 + n*16 + lm)*2048 + j64*64 + ks*32 + quad*8;
        bh[ks][n] = *(const bf16x8*)(sghb + off);
        bl[ks][n] = *(const bf16x8*)(sglb + off);
      }
    }
    #pragma unroll
    for (int m = 0; m < 8; ++m){
      #pragma unroll
      for (int ks = 0; ks < 2; ++ks){
        size_t off = (size_t)(I*128 + m*16 + lm)*2048 + j64*64 + ks*32 + quad*8;
        bf16x8 ah = *(const bf16x8*)(t1hb + off);
        bf16x8 al = *(const bf16x8*)(t1lb + off);
        #pragma unroll
        for (int n = 0; n < 2; ++n){
          su[m][n] = MFMA16(ah, bh[ks][n], su[m][n]);
          su[m][n] = MFMA16(ah, bl[ks][n], su[m][n]);
          su[m][n] = MFMA16(al, bh[ks][n], su[m][n]);
        }
      }
    }
  }
  // fused S_c = scale * Qc @ Kc^T (split for accuracy)
  const float* Qc = proj + 3*524288 + (size_t)b*131072;
  const float* Kc = proj + 4*524288 + (size_t)b*131072;
  f32x4 sc[8][2] = {};
  #pragma unroll
  for (int ks = 0; ks < 2; ++ks){
    bf16x8 bh[2], bl[2];
    #pragma unroll
    for (int n = 0; n < 2; ++n){
      int col = K*128 + w*32 + n*16 + lm;
      split8(Kc + (size_t)col*64 + ks*32 + quad*8, bh[n], bl[n]);
    }
    #pragma unroll
    for (int m = 0; m < 8; ++m){
      int row = I*128 + m*16 + lm;
      bf16x8 ah, al;
      split8(Qc + (size_t)row*64 + ks*32 + quad*8, ah, al);
      #pragma unroll
      for (int n = 0; n < 2; ++n){
        sc[m][n] = MFMA16(ah, bh[n], sc[m][n]);
        sc[m][n] = MFMA16(ah, bl[n], sc[m][n]);
        sc[m][n] = MFMA16(al, bh[n], sc[m][n]);
      }
    }
  }
  _Float16* lgb = lg + mat;
  #pragma unroll
  for (int m = 0; m < 8; ++m){
    #pragma unroll
    for (int n = 0; n < 2; ++n){
      #pragma unroll
      for (int e = 0; e < 4; ++e){
        int irow = I*128 + m*16 + quad*4 + e;
        int kcol = K*128 + w*32 + n*16 + lm;
        float xv = su[m][n][e];
        float sg = 1.0f/(1.0f + __expf(-xv));
        lgb[(size_t)irow*2048 + kcol] = (_Float16)(sc[m][n][e]*0.125f - xv*sg);
      }
    }
  }
}

// ---------------- P4: causal softmax over logits + P @ V_c^T (online, flash-style) ----------------
#define NEG_INF (-1.0e30f)
__global__ __launch_bounds__(256) void k_p4(const _Float16* __restrict__ lg,
    const unsigned short* __restrict__ vcth, const unsigned short* __restrict__ vctl,
    float* __restrict__ out){
  int b = blockIdx.x >> 5;
  int R = blockIdx.x & 31;                    // 64-row block
  __shared__ __align__(16) float Lt[64*68];
  __shared__ __align__(16) unsigned short Pt[64*64];
  __shared__ float mrow[64], lrow[64], alpha[64], Mp[256], Sp[256];
  int tid = threadIdx.x;
  int w = tid >> 6, lane = tid & 63, lm = lane & 15, quad = lane >> 4;
  const _Float16* lgb = lg + (size_t)b*4194304u + (size_t)R*64*2048;
  const unsigned short* vchb = vcth + (size_t)b*131072;
  const unsigned short* vclb = vctl + (size_t)b*131072;
  float* ob = out + ((size_t)b*2048 + (size_t)R*64)*64;
  int r_ = tid & 63, q_ = tid >> 6;
  if (tid < 64){ mrow[tid] = NEG_INF; lrow[tid] = 0.0f; }
  f32x4 acc[4] = {};
  for (int kt = 0; kt <= R; ++kt){
    __syncthreads();
    #pragma unroll
    for (int is = 0; is < 4; ++is){
      int row = is*16 + (tid >> 4);
      int f4 = tid & 15;
      f16x4 hv = *(const f16x4*)(lgb + (size_t)row*2048 + kt*64 + f4*4);
      #pragma unroll
      for (int e = 0; e < 4; ++e) Lt[row*68 + f4*4 + e] = (float)hv[e];
    }
    __syncthreads();
    { // per-row-quarter max over valid (kk <= i) entries
      int i_ = R*64 + r_;
      float mx = NEG_INF;
      #pragma unroll
      for (int j = 0; j < 16; ++j){
        int kk = kt*64 + q_*16 + j;
        float v = Lt[r_*68 + q_*16 + j];
        mx = (kk <= i_) ? fmaxf(mx, v) : mx;
      }
      Mp[r_*4 + q_] = mx;
    }
    __syncthreads();
    if (tid < 64){
      float mo = mrow[tid];
      float mn = fmaxf(fmaxf(Mp[tid*4], Mp[tid*4+1]), fmaxf(Mp[tid*4+2], Mp[tid*4+3]));
      mn = fmaxf(mo, mn);
      mrow[tid] = mn;
      alpha[tid] = __expf(mo - mn);
    }
    __syncthreads();
    { // P = exp(L-m) -> bf16 LDS (direct chunk layout), partial sums
      int i_ = R*64 + r_;
      float mn = mrow[r_];
      float s = 0.0f;
      short pv[16];
      #pragma unroll
      for (int j = 0; j < 16; ++j){
        int kk = kt*64 + q_*16 + j;
        float p = (kk <= i_) ? __expf(Lt[r_*68 + q_*16 + j] - mn) : 0.0f;
        s += p;
        pv[j] = f2bf(p);
      }
      Sp[r_*4 + q_] = s;
      bf16x8 v0, v1;
      #pragma unroll
      for (int j = 0; j < 8; ++j){ v0[j] = pv[j]; v1[j] = pv[8+j]; }
      *(bf16x8*)((char*)Pt + r_*128 + (2*q_)*16)     = v0;
      *(bf16x8*)((char*)Pt + r_*128 + (2*q_+1)*16)   = v1;
    }
    __syncthreads();
    if (tid < 64)
      lrow[tid] = lrow[tid]*alpha[tid] + (Sp[tid*4]+Sp[tid*4+1]+Sp[tid*4+2]+Sp[tid*4+3]);
    { // rescale + MFMA accumulate (V split hi/lo)
      float a0 = alpha[w*16 + quad*4 + 0];
      float a1 = alpha[w*16 + quad*4 + 1];
      float a2 = alpha[w*16 + quad*4 + 2];
      float a3 = alpha[w*16 + quad*4 + 3];
      #pragma unroll
      for (int n = 0; n < 4; ++n){ acc[n][0]*=a0; acc[n][1]*=a1; acc[n][2]*=a2; acc[n][3]*=a3; }
      #pragma unroll
      for (int ks = 0; ks < 2; ++ks){
        bf16x8 af = *(const bf16x8*)((char*)Pt + (w*16 + lm)*128 + (ks*4 + quad)*16);
        #pragma unroll
        for (int n = 0; n < 4; ++n){
          int d = n*16 + lm;
          size_t voff = (size_t)d*2048 + kt*64 + ks*32 + quad*8;
          bf16x8 vh = *(const bf16x8*)(vchb + voff);
          bf16x8 vl = *(const bf16x8*)(vclb + voff);
          acc[n] = MFMA16(af, vh, acc[n]);
          acc[n] = MFMA16(af, vl, acc[n]);
        }
      }
    }
  }
  __syncthreads();
  #pragma unroll
  for (int n = 0; n < 4; ++n){
    #pragma unroll
    for (int e = 0; e < 4; ++e){
      int row = w*16 + quad*4 + e;
      float z = lrow[row];
      ob[(size_t)row*64 + n*16 + lm] = acc[n][e] / z;
    }
  }
}

// ---------------- workspace layout (bytes) ----------------
static const size_t OFF_PROJ = 0;            // 6 x 8192x64 f32   = 12,582,912
static const size_t OFF_WTH  = 12582912;     // 6 x 64x1024 bf16  =    786,432
static const size_t OFF_WTL  = 13369344;     //                      786,432
static const size_t OFF_VCTH = 14155776;     // 4 x 64x2048 bf16  =  1,048,576
static const size_t OFF_VCTL = 15204352;     //                    1,048,576
static const size_t OFF_T1H  = 16252928;     // 4 x 2048^2 bf16   = 33,554,432
static const size_t OFF_T1L  = 49807360;
static const size_t OFF_SGH  = 83361792;
static const size_t OFF_SGL  = 116916224;
static const size_t OFF_LG   = 150470656;    // 4 x 2048^2 f16    = 33,554,432
// total = 184,025,088 bytes

extern "C" void kernel_launch(void* const* d_in, const int* in_sizes, int n_in,
                              void* d_out, int out_size, void* d_ws, size_t ws_size,
                              hipStream_t stream){
  (void)in_sizes; (void)n_in; (void)out_size; (void)ws_size;
  const float* x = (const float*)d_in[0];
  char* ws = (char*)d_ws;
  float*          proj = (float*)(ws + OFF_PROJ);
  unsigned short* wth  = (unsigned short*)(ws + OFF_WTH);
  unsigned short* wtl  = (unsigned short*)(ws + OFF_WTL);
  unsigned short* vcth = (unsigned short*)(ws + OFF_VCTH);
  unsigned short* vctl = (unsigned short*)(ws + OFF_VCTL);
  unsigned short* t1h  = (unsigned short*)(ws + OFF_T1H);
  unsigned short* t1l  = (unsigned short*)(ws + OFF_T1L);
  unsigned short* sgh  = (unsigned short*)(ws + OFF_SGH);
  unsigned short* sgl  = (unsigned short*)(ws + OFF_SGL);
  _Float16*       lg   = (_Float16*)(ws + OFF_LG);

  k_wt  <<<dim3(256,6), 256, 0, stream>>>((const float*)d_in[1], (const float*)d_in[2],
                                          (const float*)d_in[3], (const float*)d_in[4],
                                          (const float*)d_in[5], (const float*)d_in[6], wth, wtl);
  k_proj<<<dim3(128,6), 256, 0, stream>>>(x, wth, wtl, proj);
  k_vct <<<dim3(512,4), 256, 0, stream>>>(proj, vcth, vctl);
  k_p2  <<<dim3(256,4), 256, 0, stream>>>(proj, t1h, t1l, sgh, sgl);
  k_p3  <<<dim3(136,4), 256, 0, stream>>>(proj, t1h, t1l, sgh, sgl, lg);
  k_p4  <<<dim3(128),   256, 0, stream>>>(lg, vcth, vctl, (float*)d_out);
}

// Round 4
// 579.427 us; speedup vs baseline: 1.1487x; 1.1487x over previous
//
#include <hip/hip_runtime.h>
#include <hip/hip_bf16.h>

// B=4, S=2048, D=1024, DH=64. Inputs/outputs are FLOAT32 (per reference).
typedef short bf16x8 __attribute__((ext_vector_type(8)));
typedef float f32x4  __attribute__((ext_vector_type(4)));
typedef _Float16 f16x4 __attribute__((ext_vector_type(4)));
typedef _Float16 f16x8 __attribute__((ext_vector_type(8)));

#define MFMA16(a,b,c) __builtin_amdgcn_mfma_f32_16x16x32_bf16((a),(b),(c),0,0,0)

__device__ __forceinline__ short f2bf(float f){
  union { float f; unsigned u; } v; v.f = f;
  unsigned r = v.u + 0x7fffu + ((v.u >> 16) & 1u);
  return (short)(r >> 16);
}
__device__ __forceinline__ float bf2f(short h){
  union { unsigned u; float f; } v; v.u = ((unsigned)(unsigned short)h) << 16;
  return v.f;
}
// 8 consecutive fp32 -> hi/lo bf16 fragments
__device__ __forceinline__ void split8(const float* __restrict__ p, bf16x8& h, bf16x8& l){
  f32x4 a = *(const f32x4*)p;
  f32x4 b = *(const f32x4*)(p + 4);
  float t[8] = {a[0],a[1],a[2],a[3],b[0],b[1],b[2],b[3]};
  #pragma unroll
  for (int e = 0; e < 8; ++e){
    short hs = f2bf(t[e]);
    h[e] = hs;
    l[e] = f2bf(t[e] - bf2f(hs));
  }
}

// ---------------- P0: transpose+split 6 weights (1024x64 f32 -> 64x1024 bf16 hi/lo) ----------------
__global__ void k_wt(const float* w0, const float* w1, const float* w2,
                     const float* w3, const float* w4, const float* w5,
                     unsigned short* __restrict__ wth, unsigned short* __restrict__ wtl){
  int p = blockIdx.y;
  const float* wp = p==0?w0:p==1?w1:p==2?w2:p==3?w3:p==4?w4:w5;
  int idx = blockIdx.x*256 + threadIdx.x;     // [0,65536)
  int n = idx >> 10, k = idx & 1023;
  float v = wp[k*64 + n];
  short hs = f2bf(v);
  wth[(size_t)p*65536 + n*1024 + k] = (unsigned short)hs;
  wtl[(size_t)p*65536 + n*1024 + k] = (unsigned short)f2bf(v - bf2f(hs));
}

// ---------------- P1: projections x(8192x1024 f32)@w -> proj f32 (8192x64) x6, split MFMA ----------------
__global__ __launch_bounds__(256) void k_proj(const float* __restrict__ x,
                                              const unsigned short* __restrict__ wth,
                                              const unsigned short* __restrict__ wtl,
                                              float* __restrict__ proj){
  int p = blockIdx.y;
  int m_base = blockIdx.x * 64;
  int w = threadIdx.x >> 6, lane = threadIdx.x & 63;
  int lm = lane & 15, quad = lane >> 4;
  const unsigned short* wthp = wth + (size_t)p*65536;
  const unsigned short* wtlp = wtl + (size_t)p*65536;
  f32x4 acc[4] = {};
  int row = m_base + w*16 + lm;
  const float* xrow = x + (size_t)row*1024 + quad*8;
  size_t boff = (size_t)lm*1024 + quad*8;
  for (int k0 = 0; k0 < 1024; k0 += 32){
    bf16x8 ah, al;
    split8(xrow + k0, ah, al);
    #pragma unroll
    for (int t = 0; t < 4; ++t){
      bf16x8 bh = *(const bf16x8*)(wthp + boff + t*16384 + k0);
      bf16x8 bl = *(const bf16x8*)(wtlp + boff + t*16384 + k0);
      acc[t] = MFMA16(ah, bh, acc[t]);
      acc[t] = MFMA16(ah, bl, acc[t]);
      acc[t] = MFMA16(al, bh, acc[t]);
    }
  }
  float* op = proj + (size_t)p*524288;
  #pragma unroll
  for (int t = 0; t < 4; ++t){
    #pragma unroll
    for (int e = 0; e < 4; ++e){
      int r = m_base + w*16 + quad*4 + e;
      op[(size_t)r*64 + t*16 + lm] = acc[t][e];
    }
  }
}

// ---------------- P1b: V_c f32 -> V_c^T bf16 hi/lo (per batch 64 x 2048) ----------------
__global__ void k_vct(const float* __restrict__ proj,
                      unsigned short* __restrict__ vcth, unsigned short* __restrict__ vctl){
  int b = blockIdx.y;
  int idx = blockIdx.x*256 + threadIdx.x;     // [0,131072)
  int d = idx >> 11, s = idx & 2047;
  const float* vc = proj + 5*524288 + (size_t)b*131072;
  float v = vc[(size_t)s*64 + d];
  short hs = f2bf(v);
  vcth[(size_t)b*131072 + (size_t)d*2048 + s] = (unsigned short)hs;
  vctl[(size_t)b*131072 + (size_t)d*2048 + s] = (unsigned short)f2bf(v - bf2f(hs));
}

// ---------------- P2: term1 (causal, scaled) and sigmoid gate, hi/lo bf16 ----------------
template<bool TERM1>
__device__ __forceinline__ void p2_compute_store(const float* __restrict__ A, const float* __restrict__ Bm,
                 unsigned short* __restrict__ oh, unsigned short* __restrict__ ol,
                 int a128, int b128, int w, int lm, int quad){
  f32x4 acc[8][2] = {};
  #pragma unroll
  for (int ks = 0; ks < 2; ++ks){
    bf16x8 bh[2], bl[2];
    #pragma unroll
    for (int n = 0; n < 2; ++n){
      int col = b128*128 + w*32 + n*16 + lm;
      split8(Bm + (size_t)col*64 + ks*32 + quad*8, bh[n], bl[n]);
    }
    #pragma unroll
    for (int m = 0; m < 8; ++m){
      int row = a128*128 + m*16 + lm;
      bf16x8 ah, al;
      split8(A + (size_t)row*64 + ks*32 + quad*8, ah, al);
      #pragma unroll
      for (int n = 0; n < 2; ++n){
        acc[m][n] = MFMA16(ah, bh[n], acc[m][n]);
        acc[m][n] = MFMA16(ah, bl[n], acc[m][n]);
        acc[m][n] = MFMA16(al, bh[n], acc[m][n]);
      }
    }
  }
  #pragma unroll
  for (int m = 0; m < 8; ++m){
    int r64 = (a128*128 + m*16) >> 6;
    #pragma unroll
    for (int n = 0; n < 2; ++n){
      int j64 = (b128*128 + w*32 + n*16) >> 6;
      bool wr = TERM1 ? (j64 <= r64 + 1) : (j64 >= r64 - 1);
      if (wr){
        #pragma unroll
        for (int e = 0; e < 4; ++e){
          int irow = a128*128 + m*16 + quad*4 + e;
          int jcol = b128*128 + w*32 + n*16 + lm;
          float v = acc[m][n][e] * 0.125f;
          float outv;
          if (TERM1) outv = (jcol <= irow) ? v : 0.0f;
          else       outv = (jcol >  irow) ? (1.0f/(1.0f + __expf(-v))) : 0.0f;
          short hs = f2bf(outv);
          float lo = outv - bf2f(hs);
          size_t idx = (size_t)irow*2048 + jcol;
          oh[idx] = (unsigned short)hs;
          ol[idx] = (unsigned short)f2bf(lo);
        }
      }
    }
  }
}

__global__ __launch_bounds__(256) void k_p2(const float* __restrict__ proj,
    unsigned short* __restrict__ t1h, unsigned short* __restrict__ t1l,
    unsigned short* __restrict__ sgh, unsigned short* __restrict__ sgl){
  int b = blockIdx.y;
  int a128 = blockIdx.x >> 4, b128 = blockIdx.x & 15;
  int w = threadIdx.x >> 6, lane = threadIdx.x & 63;
  int lm = lane & 15, quad = lane >> 4;
  const float* Qu = proj + 0*524288 + (size_t)b*131072;
  const float* Ku = proj + 1*524288 + (size_t)b*131072;
  const float* Vu = proj + 2*524288 + (size_t)b*131072;
  const float* Qc = proj + 3*524288 + (size_t)b*131072;
  size_t mat = (size_t)b * 4194304u;
  if (b128 <= a128 + 1)
    p2_compute_store<true >(Qc, Vu, t1h + mat, t1l + mat, a128, b128, w, lm, quad);
  if (b128 >= a128 - 1)
    p2_compute_store<false>(Qu, Ku, sgh + mat, sgl + mat, a128, b128, w, lm, quad);
}

// ---------------- P3: S_u = term1 @ sig^T (split, tri-tiled, 64-row blocks, longest-first) ----------------
__global__ __launch_bounds__(256) void k_p3(const float* __restrict__ proj,
    const unsigned short* __restrict__ t1h, const unsigned short* __restrict__ t1l,
    const unsigned short* __restrict__ sgh, const unsigned short* __restrict__ sgl,
    _Float16* __restrict__ lg){
  int b = blockIdx.y;
  int v = blockIdx.x >> 1, h = blockIdx.x & 1;    // v in [0,136), h = row-half
  int I = 0, K = 0;
  #pragma unroll 1
  for (int d = 15; d >= 0; --d){                  // longest tiles (largest I-K) first
    int nd = 16 - d;
    if (v < nd){ I = d + v; K = v; break; }
    v -= nd;
  }
  int tid = threadIdx.x, w = tid >> 6, lane = tid & 63;
  int lm = lane & 15, quad = lane >> 4;
  size_t mat = (size_t)b * 4194304u;
  const unsigned short* t1hb = t1h + mat;
  const unsigned short* t1lb = t1l + mat;
  const unsigned short* sghb = sgh + mat;
  const unsigned short* sglb = sgl + mat;
  int rbase = I*128 + h*64;

  f32x4 su[4][2] = {};
  for (int j64 = 2*K; j64 <= 2*I + 1; ++j64){
    bf16x8 bh[2][2], bl[2][2];                // [ks][n]
    #pragma unroll
    for (int ks = 0; ks < 2; ++ks){
      #pragma unroll
      for (int n = 0; n < 2; ++n){
        size_t off = (size_t)(K*128 + w*32 + n*16 + lm)*2048 + j64*64 + ks*32 + quad*8;
        bh[ks][n] = *(const bf16x8*)(sghb + off);
        bl[ks][n] = *(const bf16x8*)(sglb + off);
      }
    }
    #pragma unroll
    for (int m = 0; m < 4; ++m){
      #pragma unroll
      for (int ks = 0; ks < 2; ++ks){
        size_t off = (size_t)(rbase + m*16 + lm)*2048 + j64*64 + ks*32 + quad*8;
        bf16x8 ah = *(const bf16x8*)(t1hb + off);
        bf16x8 al = *(const bf16x8*)(t1lb + off);
        #pragma unroll
        for (int n = 0; n < 2; ++n){
          su[m][n] = MFMA16(ah, bh[ks][n], su[m][n]);
          su[m][n] = MFMA16(ah, bl[ks][n], su[m][n]);
          su[m][n] = MFMA16(al, bh[ks][n], su[m][n]);
        }
      }
    }
  }
  // fused S_c = scale * Qc @ Kc^T (split for accuracy)
  const float* Qc = proj + 3*524288 + (size_t)b*131072;
  const float* Kc = proj + 4*524288 + (size_t)b*131072;
  f32x4 sc[4][2] = {};
  #pragma unroll
  for (int ks = 0; ks < 2; ++ks){
    bf16x8 bh[2], bl[2];
    #pragma unroll
    for (int n = 0; n < 2; ++n){
      int col = K*128 + w*32 + n*16 + lm;
      split8(Kc + (size_t)col*64 + ks*32 + quad*8, bh[n], bl[n]);
    }
    #pragma unroll
    for (int m = 0; m < 4; ++m){
      int row = rbase + m*16 + lm;
      bf16x8 ah, al;
      split8(Qc + (size_t)row*64 + ks*32 + quad*8, ah, al);
      #pragma unroll
      for (int n = 0; n < 2; ++n){
        sc[m][n] = MFMA16(ah, bh[n], sc[m][n]);
        sc[m][n] = MFMA16(ah, bl[n], sc[m][n]);
        sc[m][n] = MFMA16(al, bh[n], sc[m][n]);
      }
    }
  }
  _Float16* lgb = lg + mat;
  #pragma unroll
  for (int m = 0; m < 4; ++m){
    #pragma unroll
    for (int n = 0; n < 2; ++n){
      #pragma unroll
      for (int e = 0; e < 4; ++e){
        int irow = rbase + m*16 + quad*4 + e;
        int kcol = K*128 + w*32 + n*16 + lm;
        float xv = su[m][n][e];
        float sg = 1.0f/(1.0f + __expf(-xv));
        lgb[(size_t)irow*2048 + kcol] = (_Float16)(sc[m][n][e]*0.125f - xv*sg);
      }
    }
  }
}

// ---------------- P4a: per-row causal max + sum-exp (one wave per row, barrier-free) ----------------
__global__ __launch_bounds__(256) void k_p4a(const _Float16* __restrict__ lg,
    float* __restrict__ mrow, float* __restrict__ zrow){
  int b = blockIdx.y;
  int wid = blockIdx.x*4 + (threadIdx.x >> 6);
  int row = 2047 - wid;                        // longest rows first
  int lane = threadIdx.x & 63;
  const _Float16* lr = lg + (size_t)b*4194304u + (size_t)row*2048;
  float m_r = -1.0e30f, s_r = 0.0f;
  int nch = (row >> 9) + 1;
  for (int it = 0; it < nch; ++it){
    int base = it*512 + lane*8;
    if (base <= row){
      f16x8 vv = *(const f16x8*)(lr + base);
      float xs[8]; float mc = -1.0e30f;
      #pragma unroll
      for (int e = 0; e < 8; ++e){
        xs[e] = (base + e <= row) ? (float)vv[e] : -1.0e30f;
        mc = fmaxf(mc, xs[e]);
      }
      float mm = fmaxf(m_r, mc);
      float s = 0.0f;
      #pragma unroll
      for (int e = 0; e < 8; ++e)
        if (xs[e] > -1.0e29f) s += __expf(xs[e] - mm);
      s_r = (m_r > -1.0e29f ? s_r*__expf(m_r - mm) : 0.0f) + s;
      m_r = mm;
    }
  }
  #pragma unroll
  for (int off = 32; off; off >>= 1){
    float mo = __shfl_xor(m_r, off);
    float so = __shfl_xor(s_r, off);
    float mm = fmaxf(m_r, mo);
    float s = 0.0f;
    if (m_r > -1.0e29f) s += s_r*__expf(m_r - mm);
    if (mo  > -1.0e29f) s += so *__expf(mo  - mm);
    m_r = mm; s_r = s;
  }
  if (lane == 0){
    mrow[b*2048 + row] = m_r;
    zrow[b*2048 + row] = s_r;
  }
}

// ---------------- P4b: out = softmax(P) @ V_c, one wave per 16-row band, barrier-free ----------------
__global__ __launch_bounds__(256) void k_p4b(const _Float16* __restrict__ lg,
    const unsigned short* __restrict__ vcth, const unsigned short* __restrict__ vctl,
    const float* __restrict__ mrow, const float* __restrict__ zrow,
    float* __restrict__ out){
  int b = blockIdx.y;
  int band = 127 - (blockIdx.x*4 + (threadIdx.x >> 6));  // longest bands first
  int r0 = band*16;
  int lane = threadIdx.x & 63, lm = lane & 15, quad = lane >> 4;
  const _Float16* lgb = lg + (size_t)b*4194304u;
  const unsigned short* vh = vcth + (size_t)b*131072;
  const unsigned short* vl = vctl + (size_t)b*131072;
  int arow = r0 + lm;                          // this lane's A row
  float mv = mrow[b*2048 + arow];
  f32x4 acc[4] = {};
  int fc    = (r0 + 1)  >> 6;                  // chunks fully below diagonal
  int lastc = (r0 + 15) >> 6;
  for (int kt = 0; kt <= lastc; ++kt){
    bool full = kt < fc;
    #pragma unroll
    for (int ks = 0; ks < 2; ++ks){
      int jbase = kt*64 + ks*32 + quad*8;
      f16x8 Lv = *(const f16x8*)(lgb + (size_t)arow*2048 + jbase);
      bf16x8 af;
      #pragma unroll
      for (int e = 0; e < 8; ++e){
        float p = __expf((float)Lv[e] - mv);
        if (!full && (jbase + e > arow)) p = 0.0f;
        af[e] = f2bf(p);
      }
      #pragma unroll
      for (int n = 0; n < 4; ++n){
        size_t voff = (size_t)(n*16 + lm)*2048 + jbase;
        bf16x8 bh = *(const bf16x8*)(vh + voff);
        bf16x8 bl = *(const bf16x8*)(vl + voff);
        acc[n] = MFMA16(af, bh, acc[n]);
        acc[n] = MFMA16(af, bl, acc[n]);
      }
    }
  }
  float* ob = out + ((size_t)b*2048 + r0)*64;
  f32x4 zv = *(const f32x4*)(zrow + b*2048 + r0 + quad*4);
  #pragma unroll
  for (int n = 0; n < 4; ++n){
    #pragma unroll
    for (int e = 0; e < 4; ++e){
      ob[(size_t)(quad*4 + e)*64 + n*16 + lm] = acc[n][e] / zv[e];
    }
  }
}

// ---------------- workspace layout (bytes) ----------------
static const size_t OFF_PROJ = 0;            // 6 x 8192x64 f32   = 12,582,912
static const size_t OFF_WTH  = 12582912;     // 6 x 64x1024 bf16  =    786,432  (reused as mrow after proj)
static const size_t OFF_WTL  = 13369344;     //                      786,432  (reused as zrow after proj)
static const size_t OFF_VCTH = 14155776;     // 4 x 64x2048 bf16  =  1,048,576
static const size_t OFF_VCTL = 15204352;     //                    1,048,576
static const size_t OFF_T1H  = 16252928;     // 4 x 2048^2 bf16   = 33,554,432
static const size_t OFF_T1L  = 49807360;
static const size_t OFF_SGH  = 83361792;
static const size_t OFF_SGL  = 116916224;
static const size_t OFF_LG   = 150470656;    // 4 x 2048^2 f16    = 33,554,432
// total = 184,025,088 bytes

extern "C" void kernel_launch(void* const* d_in, const int* in_sizes, int n_in,
                              void* d_out, int out_size, void* d_ws, size_t ws_size,
                              hipStream_t stream){
  (void)in_sizes; (void)n_in; (void)out_size; (void)ws_size;
  const float* x = (const float*)d_in[0];
  char* ws = (char*)d_ws;
  float*          proj = (float*)(ws + OFF_PROJ);
  unsigned short* wth  = (unsigned short*)(ws + OFF_WTH);
  unsigned short* wtl  = (unsigned short*)(ws + OFF_WTL);
  unsigned short* vcth = (unsigned short*)(ws + OFF_VCTH);
  unsigned short* vctl = (unsigned short*)(ws + OFF_VCTL);
  unsigned short* t1h  = (unsigned short*)(ws + OFF_T1H);
  unsigned short* t1l  = (unsigned short*)(ws + OFF_T1L);
  unsigned short* sgh  = (unsigned short*)(ws + OFF_SGH);
  unsigned short* sgl  = (unsigned short*)(ws + OFF_SGL);
  _Float16*       lg   = (_Float16*)(ws + OFF_LG);
  float*          mbuf = (float*)(ws + OFF_WTH);   // weights dead after k_proj
  float*          zbuf = (float*)(ws + OFF_WTL);

  k_wt  <<<dim3(256,6), 256, 0, stream>>>((const float*)d_in[1], (const float*)d_in[2],
                                          (const float*)d_in[3], (const float*)d_in[4],
                                          (const float*)d_in[5], (const float*)d_in[6], wth, wtl);
  k_proj<<<dim3(128,6), 256, 0, stream>>>(x, wth, wtl, proj);
  k_vct <<<dim3(512,4), 256, 0, stream>>>(proj, vcth, vctl);
  k_p2  <<<dim3(256,4), 256, 0, stream>>>(proj, t1h, t1l, sgh, sgl);
  k_p3  <<<dim3(272,4), 256, 0, stream>>>(proj, t1h, t1l, sgh, sgl, lg);
  k_p4a <<<dim3(512,4), 256, 0, stream>>>(lg, mbuf, zbuf);
  k_p4b <<<dim3(32,4),  256, 0, stream>>>(lg, vcth, vctl, mbuf, zbuf, (float*)d_out);
}

// Round 5
// 320.378 us; speedup vs baseline: 2.0776x; 1.8086x over previous
//
#include <hip/hip_runtime.h>
#include <hip/hip_bf16.h>

// B=4, S=2048, D=1024, DH=64. Inputs/outputs are FLOAT32 (per reference).
typedef short bf16x8 __attribute__((ext_vector_type(8)));
typedef float f32x4  __attribute__((ext_vector_type(4)));
typedef _Float16 f16x4 __attribute__((ext_vector_type(4)));
typedef _Float16 f16x8 __attribute__((ext_vector_type(8)));

#define MFMA16(a,b,c) __builtin_amdgcn_mfma_f32_16x16x32_bf16((a),(b),(c),0,0,0)

// async global->LDS: 16B per lane, lane i lands at lds_base + i*16
#define GLDS16(g,l) __builtin_amdgcn_global_load_lds( \
    (const __attribute__((address_space(1))) void*)(g), \
    (__attribute__((address_space(3))) void*)(l), 16, 0, 0)

__device__ __forceinline__ short f2bf(float f){
  union { float f; unsigned u; } v; v.f = f;
  unsigned r = v.u + 0x7fffu + ((v.u >> 16) & 1u);
  return (short)(r >> 16);
}
__device__ __forceinline__ float bf2f(short h){
  union { unsigned u; float f; } v; v.u = ((unsigned)(unsigned short)h) << 16;
  return v.f;
}
__device__ __forceinline__ void split8(const float* __restrict__ p, bf16x8& h, bf16x8& l){
  f32x4 a = *(const f32x4*)p;
  f32x4 b = *(const f32x4*)(p + 4);
  float t[8] = {a[0],a[1],a[2],a[3],b[0],b[1],b[2],b[3]};
  #pragma unroll
  for (int e = 0; e < 8; ++e){
    short hs = f2bf(t[e]);
    h[e] = hs;
    l[e] = f2bf(t[e] - bf2f(hs));
  }
}
__device__ __forceinline__ void split8v(f32x4 a, f32x4 b, bf16x8& h, bf16x8& l){
  float t[8] = {a[0],a[1],a[2],a[3],b[0],b[1],b[2],b[3]};
  #pragma unroll
  for (int e = 0; e < 8; ++e){
    short hs = f2bf(t[e]);
    h[e] = hs;
    l[e] = f2bf(t[e] - bf2f(hs));
  }
}

// ---------------- P0: transpose+split 6 weights (1024x64 f32 -> 64x1024 bf16 hi/lo) ----------------
__global__ void k_wt(const float* w0, const float* w1, const float* w2,
                     const float* w3, const float* w4, const float* w5,
                     unsigned short* __restrict__ wth, unsigned short* __restrict__ wtl){
  int p = blockIdx.y;
  const float* wp = p==0?w0:p==1?w1:p==2?w2:p==3?w3:p==4?w4:w5;
  int idx = blockIdx.x*256 + threadIdx.x;     // [0,65536)
  int n = idx >> 10, k = idx & 1023;
  float v = wp[k*64 + n];
  short hs = f2bf(v);
  wth[(size_t)p*65536 + n*1024 + k] = (unsigned short)hs;
  wtl[(size_t)p*65536 + n*1024 + k] = (unsigned short)f2bf(v - bf2f(hs));
}

// ---------------- P1: all 6 projections in one pass, LDS-staged ----------------
// grid: 64 row-blocks (128 rows) x 6 p, p inner for x L2/L3 reuse. 256 thr.
__global__ __launch_bounds__(256) void k_proj(const float* __restrict__ x,
                                              const unsigned short* __restrict__ wth,
                                              const unsigned short* __restrict__ wtl,
                                              float* __restrict__ proj){
  __shared__ __align__(16) char sm[49152];   // xh 16K | xl 16K | wh 8K | wl 8K
  int blk = blockIdx.x;
  int rb = blk/6, p = blk - rb*6;
  int tid = threadIdx.x, w = tid >> 6, lane = tid & 63;
  int lm = lane & 15, quad = lane >> 4;
  int rloc = tid >> 1, ch = tid & 1;         // x staging: row, col-half(32 f32)
  int srow = lane >> 3, scg = (lane & 7) ^ srow;  // DMA staging consts
  const float* xrow = x + (size_t)(rb*128 + rloc)*1024 + ch*32;
  const char* wthp = (const char*)wth + (size_t)p*131072;
  const char* wtlp = (const char*)wtl + (size_t)p*131072;
  int wm = w*32;
  f32x4 acc[2][4] = {};
  for (int k0 = 0; k0 < 1024; k0 += 64){
    __syncthreads();
    // stage weights (64 c-rows x 64 k) hi/lo via DMA
    #pragma unroll
    for (int i2 = 0; i2 < 2; ++i2){
      int i = w*2 + i2;
      size_t g = (size_t)(i*8 + srow)*2048 + (size_t)k0*2 + scg*16;
      GLDS16(wthp + g, sm + 32768 + i*1024);
      GLDS16(wtlp + g, sm + 40960 + i*1024);
    }
    // stage x (128 rows x 64 k) through regs, convert to hi/lo
    f32x4 xv[8];
    #pragma unroll
    for (int j = 0; j < 8; ++j) xv[j] = *(const f32x4*)(xrow + k0 + j*4);
    #pragma unroll
    for (int j = 0; j < 4; ++j){
      bf16x8 h, l;
      split8v(xv[2*j], xv[2*j+1], h, l);
      int slot = (ch*4 + j) ^ (rloc & 7);
      *(bf16x8*)(sm +         rloc*128 + slot*16) = h;
      *(bf16x8*)(sm + 16384 + rloc*128 + slot*16) = l;
    }
    __syncthreads();
    #pragma unroll
    for (int ks = 0; ks < 2; ++ks){
      bf16x8 bh[4], bl[4];
      #pragma unroll
      for (int n = 0; n < 4; ++n){
        int off = (n*16 + lm)*128 + (((ks*4+quad) ^ (lm&7))*16);
        bh[n] = *(const bf16x8*)(sm + 32768 + off);
        bl[n] = *(const bf16x8*)(sm + 40960 + off);
      }
      #pragma unroll
      for (int m = 0; m < 2; ++m){
        int off = (wm + m*16 + lm)*128 + (((ks*4+quad) ^ (lm&7))*16);
        bf16x8 ah = *(const bf16x8*)(sm + off);
        bf16x8 al = *(const bf16x8*)(sm + 16384 + off);
        #pragma unroll
        for (int n = 0; n < 4; ++n){
          acc[m][n] = MFMA16(ah, bh[n], acc[m][n]);
          acc[m][n] = MFMA16(ah, bl[n], acc[m][n]);
          acc[m][n] = MFMA16(al, bh[n], acc[m][n]);
        }
      }
    }
  }
  float* op = proj + (size_t)p*524288;
  #pragma unroll
  for (int m = 0; m < 2; ++m){
    #pragma unroll
    for (int n = 0; n < 4; ++n){
      #pragma unroll
      for (int e = 0; e < 4; ++e){
        int r = rb*128 + wm + m*16 + quad*4 + e;
        op[(size_t)r*64 + n*16 + lm] = acc[m][n][e];
      }
    }
  }
}

// ---------------- P1b: V_c f32 -> V_c^T bf16 hi/lo, LDS transpose ----------------
__global__ void k_vct(const float* __restrict__ proj,
                      unsigned short* __restrict__ vcth, unsigned short* __restrict__ vctl){
  __shared__ float T[64][65];
  int b = blockIdx.y, st = blockIdx.x;       // s-tile [0,32)
  int tid = threadIdx.x;
  const float* vc = proj + 5*524288 + (size_t)b*131072;
  int sloc = tid >> 2, cp = (tid & 3)*16;
  #pragma unroll
  for (int j = 0; j < 4; ++j){
    f32x4 v = *(const f32x4*)(vc + (size_t)(st*64 + sloc)*64 + cp + j*4);
    #pragma unroll
    for (int e = 0; e < 4; ++e) T[sloc][cp + j*4 + e] = v[e];
  }
  __syncthreads();
  int d = tid >> 2, sp = (tid & 3)*16;
  bf16x8 h0, h1, l0, l1;
  #pragma unroll
  for (int j = 0; j < 8; ++j){
    float f = T[sp + j][d];
    short hs = f2bf(f); h0[j] = hs; l0[j] = f2bf(f - bf2f(hs));
  }
  #pragma unroll
  for (int j = 0; j < 8; ++j){
    float f = T[sp + 8 + j][d];
    short hs = f2bf(f); h1[j] = hs; l1[j] = f2bf(f - bf2f(hs));
  }
  size_t o = (size_t)b*131072 + (size_t)d*2048 + st*64 + sp;
  *(bf16x8*)(vcth + o) = h0; *(bf16x8*)(vcth + o + 8) = h1;
  *(bf16x8*)(vctl + o) = l0; *(bf16x8*)(vctl + o + 8) = l1;
}

// ---------------- P2: term1 (causal, scaled) and sigmoid gate, hi/lo bf16 (unchanged) ----------------
template<bool TERM1>
__device__ __forceinline__ void p2_compute_store(const float* __restrict__ A, const float* __restrict__ Bm,
                 unsigned short* __restrict__ oh, unsigned short* __restrict__ ol,
                 int a128, int b128, int w, int lm, int quad){
  f32x4 acc[8][2] = {};
  #pragma unroll
  for (int ks = 0; ks < 2; ++ks){
    bf16x8 bh[2], bl[2];
    #pragma unroll
    for (int n = 0; n < 2; ++n){
      int col = b128*128 + w*32 + n*16 + lm;
      split8(Bm + (size_t)col*64 + ks*32 + quad*8, bh[n], bl[n]);
    }
    #pragma unroll
    for (int m = 0; m < 8; ++m){
      int row = a128*128 + m*16 + lm;
      bf16x8 ah, al;
      split8(A + (size_t)row*64 + ks*32 + quad*8, ah, al);
      #pragma unroll
      for (int n = 0; n < 2; ++n){
        acc[m][n] = MFMA16(ah, bh[n], acc[m][n]);
        acc[m][n] = MFMA16(ah, bl[n], acc[m][n]);
        acc[m][n] = MFMA16(al, bh[n], acc[m][n]);
      }
    }
  }
  #pragma unroll
  for (int m = 0; m < 8; ++m){
    int r64 = (a128*128 + m*16) >> 6;
    #pragma unroll
    for (int n = 0; n < 2; ++n){
      int j64 = (b128*128 + w*32 + n*16) >> 6;
      bool wr = TERM1 ? (j64 <= r64 + 1) : (j64 >= r64 - 1);
      if (wr){
        #pragma unroll
        for (int e = 0; e < 4; ++e){
          int irow = a128*128 + m*16 + quad*4 + e;
          int jcol = b128*128 + w*32 + n*16 + lm;
          float v = acc[m][n][e] * 0.125f;
          float outv;
          if (TERM1) outv = (jcol <= irow) ? v : 0.0f;
          else       outv = (jcol >  irow) ? (1.0f/(1.0f + __expf(-v))) : 0.0f;
          short hs = f2bf(outv);
          float lo = outv - bf2f(hs);
          size_t idx = (size_t)irow*2048 + jcol;
          oh[idx] = (unsigned short)hs;
          ol[idx] = (unsigned short)f2bf(lo);
        }
      }
    }
  }
}

__global__ __launch_bounds__(256) void k_p2(const float* __restrict__ proj,
    unsigned short* __restrict__ t1h, unsigned short* __restrict__ t1l,
    unsigned short* __restrict__ sgh, unsigned short* __restrict__ sgl){
  int b = blockIdx.y;
  int a128 = blockIdx.x >> 4, b128 = blockIdx.x & 15;
  int w = threadIdx.x >> 6, lane = threadIdx.x & 63;
  int lm = lane & 15, quad = lane >> 4;
  const float* Qu = proj + 0*524288 + (size_t)b*131072;
  const float* Ku = proj + 1*524288 + (size_t)b*131072;
  const float* Vu = proj + 2*524288 + (size_t)b*131072;
  const float* Qc = proj + 3*524288 + (size_t)b*131072;
  size_t mat = (size_t)b * 4194304u;
  if (b128 <= a128 + 1)
    p2_compute_store<true >(Qc, Vu, t1h + mat, t1l + mat, a128, b128, w, lm, quad);
  if (b128 >= a128 - 1)
    p2_compute_store<false>(Qu, Ku, sgh + mat, sgl + mat, a128, b128, w, lm, quad);
}

// ---------------- P3: S_u = term1 @ sig^T — LDS-staged m97-style GEMM, tri-tiled ----------------
__global__ __launch_bounds__(256,2) void k_p3(const float* __restrict__ proj,
    const unsigned short* __restrict__ t1h, const unsigned short* __restrict__ t1l,
    const unsigned short* __restrict__ sgh, const unsigned short* __restrict__ sgl,
    _Float16* __restrict__ lg){
  __shared__ __align__(16) char sm[65536];   // Ah | Al | Bh | Bl (16K each)
  int b = blockIdx.y;
  int v = blockIdx.x, I = 0, K = 0;
  #pragma unroll 1
  for (int d = 15; d >= 0; --d){             // longest (I-K) first
    int nd = 16 - d;
    if (v < nd){ I = d + v; K = v; break; }
    v -= nd;
  }
  int tid = threadIdx.x, w = tid >> 6, lane = tid & 63;
  int lm = lane & 15, quad = lane >> 4;
  size_t mat = (size_t)b * 4194304u;
  const char* Ahg = (const char*)(t1h + mat);
  const char* Alg = (const char*)(t1l + mat);
  const char* Bhg = (const char*)(sgh + mat);
  const char* Blg = (const char*)(sgl + mat);
  int srow = lane >> 3, scg = (lane & 7) ^ srow;
  int wm = (w & 1)*64, wn = (w >> 1)*64;

  f32x4 su[4][4] = {};
  for (int j64 = 2*K; j64 <= 2*I + 1; ++j64){
    __syncthreads();
    size_t colb = (size_t)j64*128 + scg*16;
    #pragma unroll
    for (int i2 = 0; i2 < 4; ++i2){
      int i = w*4 + i2;                      // instr 0..15 per buffer
      int rl = i*8 + srow;                   // local row 0..127
      size_t ga = (size_t)(I*128 + rl)*4096 + colb;
      size_t gb = (size_t)(K*128 + rl)*4096 + colb;
      GLDS16(Ahg + ga, sm +         i*1024);
      GLDS16(Alg + ga, sm + 16384 + i*1024);
      GLDS16(Bhg + gb, sm + 32768 + i*1024);
      GLDS16(Blg + gb, sm + 49152 + i*1024);
    }
    __syncthreads();
    #pragma unroll
    for (int ks = 0; ks < 2; ++ks){
      bf16x8 bh[4], bl[4];
      #pragma unroll
      for (int n = 0; n < 4; ++n){
        int off = (wn + n*16 + lm)*128 + (((ks*4+quad) ^ (lm&7))*16);
        bh[n] = *(const bf16x8*)(sm + 32768 + off);
        bl[n] = *(const bf16x8*)(sm + 49152 + off);
      }
      #pragma unroll
      for (int m = 0; m < 4; ++m){
        int off = (wm + m*16 + lm)*128 + (((ks*4+quad) ^ (lm&7))*16);
        bf16x8 ah = *(const bf16x8*)(sm + off);
        bf16x8 al = *(const bf16x8*)(sm + 16384 + off);
        #pragma unroll
        for (int n = 0; n < 4; ++n){
          su[m][n] = MFMA16(ah, bh[n], su[m][n]);
          su[m][n] = MFMA16(ah, bl[n], su[m][n]);
          su[m][n] = MFMA16(al, bh[n], su[m][n]);
        }
      }
    }
  }
  // fused S_c = Qc @ Kc^T (split), direct global (one-time)
  const float* Qc = proj + 3*524288 + (size_t)b*131072;
  const float* Kc = proj + 4*524288 + (size_t)b*131072;
  f32x4 sc[4][4] = {};
  #pragma unroll
  for (int ks = 0; ks < 2; ++ks){
    bf16x8 kh[4], kl[4];
    #pragma unroll
    for (int n = 0; n < 4; ++n){
      int col = K*128 + wn + n*16 + lm;
      split8(Kc + (size_t)col*64 + ks*32 + quad*8, kh[n], kl[n]);
    }
    #pragma unroll
    for (int m = 0; m < 4; ++m){
      int row = I*128 + wm + m*16 + lm;
      bf16x8 ah, al;
      split8(Qc + (size_t)row*64 + ks*32 + quad*8, ah, al);
      #pragma unroll
      for (int n = 0; n < 4; ++n){
        sc[m][n] = MFMA16(ah, kh[n], sc[m][n]);
        sc[m][n] = MFMA16(ah, kl[n], sc[m][n]);
        sc[m][n] = MFMA16(al, kh[n], sc[m][n]);
      }
    }
  }
  _Float16* lgb = lg + mat;
  #pragma unroll
  for (int m = 0; m < 4; ++m){
    #pragma unroll
    for (int n = 0; n < 4; ++n){
      #pragma unroll
      for (int e = 0; e < 4; ++e){
        int irow = I*128 + wm + m*16 + quad*4 + e;
        int kcol = K*128 + wn + n*16 + lm;
        float xv = su[m][n][e];
        float sg = 1.0f/(1.0f + __expf(-xv));
        lgb[(size_t)irow*2048 + kcol] = (_Float16)(sc[m][n][e]*0.125f - xv*sg);
      }
    }
  }
}

// ---------------- P4a: per-row causal max + sum-exp (one wave per row) ----------------
__global__ __launch_bounds__(256) void k_p4a(const _Float16* __restrict__ lg,
    float* __restrict__ mrow, float* __restrict__ zrow){
  int b = blockIdx.y;
  int wid = blockIdx.x*4 + (threadIdx.x >> 6);
  int row = 2047 - wid;                        // longest rows first
  int lane = threadIdx.x & 63;
  const _Float16* lr = lg + (size_t)b*4194304u + (size_t)row*2048;
  float m_r = -1.0e30f, s_r = 0.0f;
  int nch = (row >> 9) + 1;
  for (int it = 0; it < nch; ++it){
    int base = it*512 + lane*8;
    if (base <= row){
      f16x8 vv = *(const f16x8*)(lr + base);
      float xs[8]; float mc = -1.0e30f;
      #pragma unroll
      for (int e = 0; e < 8; ++e){
        xs[e] = (base + e <= row) ? (float)vv[e] : -1.0e30f;
        mc = fmaxf(mc, xs[e]);
      }
      float mm = fmaxf(m_r, mc);
      float s = 0.0f;
      #pragma unroll
      for (int e = 0; e < 8; ++e)
        if (xs[e] > -1.0e29f) s += __expf(xs[e] - mm);
      s_r = (m_r > -1.0e29f ? s_r*__expf(m_r - mm) : 0.0f) + s;
      m_r = mm;
    }
  }
  #pragma unroll
  for (int off = 32; off; off >>= 1){
    float mo = __shfl_xor(m_r, off);
    float so = __shfl_xor(s_r, off);
    float mm = fmaxf(m_r, mo);
    float s = 0.0f;
    if (m_r > -1.0e29f) s += s_r*__expf(m_r - mm);
    if (mo  > -1.0e29f) s += so *__expf(mo  - mm);
    m_r = mm; s_r = s;
  }
  if (lane == 0){
    mrow[b*2048 + row] = m_r;
    zrow[b*2048 + row] = s_r;
  }
}

// ---------------- P4b: out = softmax(P) @ V_c — 16-row band/block, kt split across 4 waves ----------------
__global__ __launch_bounds__(256) void k_p4b(const _Float16* __restrict__ lg,
    const unsigned short* __restrict__ vcth, const unsigned short* __restrict__ vctl,
    const float* __restrict__ mrow, const float* __restrict__ zrow,
    float* __restrict__ out){
  __shared__ __align__(16) float Ot[4][16][64];
  __shared__ __align__(16) _Float16 Ls[4][16][64];
  int b = blockIdx.y;
  int band = 127 - blockIdx.x;                 // longest first
  int r0 = band*16;
  int tid = threadIdx.x, w = tid >> 6, lane = tid & 63;
  int lm = lane & 15, quad = lane >> 4;
  const _Float16* lgb = lg + (size_t)b*4194304u;
  const unsigned short* vh = vcth + (size_t)b*131072;
  const unsigned short* vl = vctl + (size_t)b*131072;
  int arow = r0 + lm;
  float mv = mrow[b*2048 + arow];
  int nkt = ((r0 + 15) >> 6) + 1;
  int fc = (r0 + 1) >> 6;
  int sr = lane >> 2, sc = (lane & 3)*16;      // L staging: row, 32B col
  f32x4 acc[4] = {};
  for (int kt = w; kt < nkt; kt += 4){
    // stage this wave's 16x64 L chunk (coalesced), wave-private
    const _Float16* src = lgb + (size_t)(r0 + sr)*2048 + kt*64 + sc;
    *(f16x8*)&Ls[w][sr][sc]     = *(const f16x8*)src;
    *(f16x8*)&Ls[w][sr][sc + 8] = *(const f16x8*)(src + 8);
    bool full = kt < fc;
    #pragma unroll
    for (int ks = 0; ks < 2; ++ks){
      int jbase = kt*64 + ks*32 + quad*8;
      f16x8 Lv = *(const f16x8*)&Ls[w][lm][ks*32 + quad*8];
      bf16x8 af;
      #pragma unroll
      for (int e = 0; e < 8; ++e){
        float p = __expf((float)Lv[e] - mv);
        if (!full && (jbase + e > arow)) p = 0.0f;
        af[e] = f2bf(p);
      }
      #pragma unroll
      for (int n = 0; n < 4; ++n){
        size_t voff = (size_t)(n*16 + lm)*2048 + jbase;
        bf16x8 bh = *(const bf16x8*)(vh + voff);
        bf16x8 bl = *(const bf16x8*)(vl + voff);
        acc[n] = MFMA16(af, bh, acc[n]);
        acc[n] = MFMA16(af, bl, acc[n]);
      }
    }
  }
  #pragma unroll
  for (int n = 0; n < 4; ++n)
    #pragma unroll
    for (int e = 0; e < 4; ++e)
      Ot[w][quad*4 + e][n*16 + lm] = acc[n][e];
  __syncthreads();
  int row = tid >> 4, c4 = (tid & 15)*4;
  f32x4 s = *(const f32x4*)&Ot[0][row][c4];
  #pragma unroll
  for (int ww = 1; ww < 4; ++ww){
    f32x4 t = *(const f32x4*)&Ot[ww][row][c4];
    s[0]+=t[0]; s[1]+=t[1]; s[2]+=t[2]; s[3]+=t[3];
  }
  float z = zrow[b*2048 + r0 + row];
  f32x4 o = { s[0]/z, s[1]/z, s[2]/z, s[3]/z };
  *(f32x4*)(out + ((size_t)b*2048 + r0 + row)*64 + c4) = o;
}

// ---------------- workspace layout (bytes) ----------------
static const size_t OFF_PROJ = 0;            // 6 x 8192x64 f32   = 12,582,912
static const size_t OFF_WTH  = 12582912;     // 6 x 64x1024 bf16  (reused as mrow after proj)
static const size_t OFF_WTL  = 13369344;     //                   (reused as zrow after proj)
static const size_t OFF_VCTH = 14155776;     // 4 x 64x2048 bf16
static const size_t OFF_VCTL = 15204352;
static const size_t OFF_T1H  = 16252928;     // 4 x 2048^2 bf16
static const size_t OFF_T1L  = 49807360;
static const size_t OFF_SGH  = 83361792;
static const size_t OFF_SGL  = 116916224;
static const size_t OFF_LG   = 150470656;    // 4 x 2048^2 f16
// total = 184,025,088 bytes

extern "C" void kernel_launch(void* const* d_in, const int* in_sizes, int n_in,
                              void* d_out, int out_size, void* d_ws, size_t ws_size,
                              hipStream_t stream){
  (void)in_sizes; (void)n_in; (void)out_size; (void)ws_size;
  const float* x = (const float*)d_in[0];
  char* ws = (char*)d_ws;
  float*          proj = (float*)(ws + OFF_PROJ);
  unsigned short* wth  = (unsigned short*)(ws + OFF_WTH);
  unsigned short* wtl  = (unsigned short*)(ws + OFF_WTL);
  unsigned short* vcth = (unsigned short*)(ws + OFF_VCTH);
  unsigned short* vctl = (unsigned short*)(ws + OFF_VCTL);
  unsigned short* t1h  = (unsigned short*)(ws + OFF_T1H);
  unsigned short* t1l  = (unsigned short*)(ws + OFF_T1L);
  unsigned short* sgh  = (unsigned short*)(ws + OFF_SGH);
  unsigned short* sgl  = (unsigned short*)(ws + OFF_SGL);
  _Float16*       lg   = (_Float16*)(ws + OFF_LG);
  float*          mbuf = (float*)(ws + OFF_WTH);   // weights dead after k_proj
  float*          zbuf = (float*)(ws + OFF_WTL);

  k_wt  <<<dim3(256,6), 256, 0, stream>>>((const float*)d_in[1], (const float*)d_in[2],
                                          (const float*)d_in[3], (const float*)d_in[4],
                                          (const float*)d_in[5], (const float*)d_in[6], wth, wtl);
  k_proj<<<dim3(384),   256, 0, stream>>>(x, wth, wtl, proj);
  k_vct <<<dim3(32,4),  256, 0, stream>>>(proj, vcth, vctl);
  k_p2  <<<dim3(256,4), 256, 0, stream>>>(proj, t1h, t1l, sgh, sgl);
  k_p3  <<<dim3(136,4), 256, 0, stream>>>(proj, t1h, t1l, sgh, sgl, lg);
  k_p4a <<<dim3(512,4), 256, 0, stream>>>(lg, mbuf, zbuf);
  k_p4b <<<dim3(128,4), 256, 0, stream>>>(lg, vcth, vctl, mbuf, zbuf, (float*)d_out);
}

// Round 6
// 232.568 us; speedup vs baseline: 2.8620x; 1.3776x over previous
//
#include <hip/hip_runtime.h>
#include <hip/hip_bf16.h>

// B=4, S=2048, D=1024, DH=64. Inputs/outputs are FLOAT32 (per reference).
typedef short bf16x8 __attribute__((ext_vector_type(8)));
typedef float f32x4  __attribute__((ext_vector_type(4)));
typedef _Float16 f16x4 __attribute__((ext_vector_type(4)));
typedef _Float16 f16x8 __attribute__((ext_vector_type(8)));

#define MFMA16(a,b,c)  __builtin_amdgcn_mfma_f32_16x16x32_bf16((a),(b),(c),0,0,0)
#define MFMAF16(a,b,c) __builtin_amdgcn_mfma_f32_16x16x32_f16((a),(b),(c),0,0,0)

// async global->LDS: 16B per lane, lane i lands at lds_base + i*16
#define GLDS16(g,l) __builtin_amdgcn_global_load_lds( \
    (const __attribute__((address_space(1))) void*)(g), \
    (__attribute__((address_space(3))) void*)(l), 16, 0, 0)

__device__ __forceinline__ short f2bf(float f){
  union { float f; unsigned u; } v; v.f = f;
  unsigned r = v.u + 0x7fffu + ((v.u >> 16) & 1u);
  return (short)(r >> 16);
}
__device__ __forceinline__ float bf2f(short h){
  union { unsigned u; float f; } v; v.u = ((unsigned)(unsigned short)h) << 16;
  return v.f;
}
__device__ __forceinline__ void split8v(f32x4 a, f32x4 b, bf16x8& h, bf16x8& l){
  float t[8] = {a[0],a[1],a[2],a[3],b[0],b[1],b[2],b[3]};
  #pragma unroll
  for (int e = 0; e < 8; ++e){
    short hs = f2bf(t[e]);
    h[e] = hs;
    l[e] = f2bf(t[e] - bf2f(hs));
  }
}

// ---------------- P0: transpose+split 6 weights (1024x64 f32 -> 64x1024 bf16 hi/lo) ----------------
__global__ void k_wt(const float* w0, const float* w1, const float* w2,
                     const float* w3, const float* w4, const float* w5,
                     unsigned short* __restrict__ wth, unsigned short* __restrict__ wtl){
  int p = blockIdx.y;
  const float* wp = p==0?w0:p==1?w1:p==2?w2:p==3?w3:p==4?w4:w5;
  int idx = blockIdx.x*256 + threadIdx.x;     // [0,65536)
  int n = idx >> 10, k = idx & 1023;
  float v = wp[k*64 + n];
  short hs = f2bf(v);
  wth[(size_t)p*65536 + n*1024 + k] = (unsigned short)hs;
  wtl[(size_t)p*65536 + n*1024 + k] = (unsigned short)f2bf(v - bf2f(hs));
}

// ---------------- P1: all 6 projections, LDS-staged; emits f32 + bf16 hi/lo ----------------
__global__ __launch_bounds__(256) void k_proj(const float* __restrict__ x,
                                              const unsigned short* __restrict__ wth,
                                              const unsigned short* __restrict__ wtl,
                                              float* __restrict__ proj,
                                              unsigned short* __restrict__ projh,
                                              unsigned short* __restrict__ projl){
  __shared__ __align__(16) char sm[49152];   // xh 16K | xl 16K | wh 8K | wl 8K
  int blk = blockIdx.x;
  int rb = blk/6, p = blk - rb*6;
  int tid = threadIdx.x, w = tid >> 6, lane = tid & 63;
  int lm = lane & 15, quad = lane >> 4;
  int rloc = tid >> 1, ch = tid & 1;
  int srow = lane >> 3, scg = (lane & 7) ^ srow;
  const float* xrow = x + (size_t)(rb*128 + rloc)*1024 + ch*32;
  const char* wthp = (const char*)wth + (size_t)p*131072;
  const char* wtlp = (const char*)wtl + (size_t)p*131072;
  int wm = w*32;
  f32x4 acc[2][4] = {};
  for (int k0 = 0; k0 < 1024; k0 += 64){
    __syncthreads();
    #pragma unroll
    for (int i2 = 0; i2 < 2; ++i2){
      int i = w*2 + i2;
      size_t g = (size_t)(i*8 + srow)*2048 + (size_t)k0*2 + scg*16;
      GLDS16(wthp + g, sm + 32768 + i*1024);
      GLDS16(wtlp + g, sm + 40960 + i*1024);
    }
    f32x4 xv[8];
    #pragma unroll
    for (int j = 0; j < 8; ++j) xv[j] = *(const f32x4*)(xrow + k0 + j*4);
    #pragma unroll
    for (int j = 0; j < 4; ++j){
      bf16x8 h, l;
      split8v(xv[2*j], xv[2*j+1], h, l);
      int slot = (ch*4 + j) ^ (rloc & 7);
      *(bf16x8*)(sm +         rloc*128 + slot*16) = h;
      *(bf16x8*)(sm + 16384 + rloc*128 + slot*16) = l;
    }
    __syncthreads();
    #pragma unroll
    for (int ks = 0; ks < 2; ++ks){
      bf16x8 bh[4], bl[4];
      #pragma unroll
      for (int n = 0; n < 4; ++n){
        int off = (n*16 + lm)*128 + (((ks*4+quad) ^ (lm&7))*16);
        bh[n] = *(const bf16x8*)(sm + 32768 + off);
        bl[n] = *(const bf16x8*)(sm + 40960 + off);
      }
      #pragma unroll
      for (int m = 0; m < 2; ++m){
        int off = (wm + m*16 + lm)*128 + (((ks*4+quad) ^ (lm&7))*16);
        bf16x8 ah = *(const bf16x8*)(sm + off);
        bf16x8 al = *(const bf16x8*)(sm + 16384 + off);
        #pragma unroll
        for (int n = 0; n < 4; ++n){
          acc[m][n] = MFMA16(ah, bh[n], acc[m][n]);
          acc[m][n] = MFMA16(ah, bl[n], acc[m][n]);
          acc[m][n] = MFMA16(al, bh[n], acc[m][n]);
        }
      }
    }
  }
  float* op = proj + (size_t)p*524288;
  unsigned short* oph = projh + (size_t)p*524288;
  unsigned short* opl = projl + (size_t)p*524288;
  #pragma unroll
  for (int m = 0; m < 2; ++m){
    #pragma unroll
    for (int n = 0; n < 4; ++n){
      #pragma unroll
      for (int e = 0; e < 4; ++e){
        int r = rb*128 + wm + m*16 + quad*4 + e;
        float f = acc[m][n][e];
        op[(size_t)r*64 + n*16 + lm] = f;
        short hs = f2bf(f);
        oph[(size_t)r*64 + n*16 + lm] = (unsigned short)hs;
        opl[(size_t)r*64 + n*16 + lm] = (unsigned short)f2bf(f - bf2f(hs));
      }
    }
  }
}

// ---------------- P1b: V_c f32 -> V_c^T fp16 (per batch 64 x 2048) ----------------
__global__ void k_vct(const float* __restrict__ proj, _Float16* __restrict__ vct){
  __shared__ float T[64][65];
  int b = blockIdx.y, st = blockIdx.x;       // s-tile [0,32)
  int tid = threadIdx.x;
  const float* vc = proj + 5*524288 + (size_t)b*131072;
  int sloc = tid >> 2, cp = (tid & 3)*16;
  #pragma unroll
  for (int j = 0; j < 4; ++j){
    f32x4 v = *(const f32x4*)(vc + (size_t)(st*64 + sloc)*64 + cp + j*4);
    #pragma unroll
    for (int e = 0; e < 4; ++e) T[sloc][cp + j*4 + e] = v[e];
  }
  __syncthreads();
  int d = tid >> 2, sp = (tid & 3)*16;
  f16x8 h0, h1;
  #pragma unroll
  for (int j = 0; j < 8; ++j) h0[j] = (_Float16)T[sp + j][d];
  #pragma unroll
  for (int j = 0; j < 8; ++j) h1[j] = (_Float16)T[sp + 8 + j][d];
  size_t o = (size_t)b*131072 + (size_t)d*2048 + st*64 + sp;
  *(f16x8*)(vct + o) = h0; *(f16x8*)(vct + o + 8) = h1;
}

// ---------------- P2: term1 / sigmoid-gate tiles, LDS-staged split GEMM -> fp16 ----------------
__global__ __launch_bounds__(256,2) void k_p2(
    const unsigned short* __restrict__ ph, const unsigned short* __restrict__ pl,
    _Float16* __restrict__ t1, _Float16* __restrict__ sg){
  __shared__ __align__(16) char sm[65536];   // Ah | Al | Bh | Bl (16K each); reused for epilogue
  int b = blockIdx.y;
  int t = blockIdx.x;                        // [0,272): 136 term1 tiles + 136 sig tiles
  bool isSig = t >= 136;
  if (isSig) t -= 136;
  int a = 0, bb = 0;
  #pragma unroll 1
  for (int aa = 0; aa < 16; ++aa){
    int c = isSig ? (16 - aa) : (aa + 1);
    if (t < c){ a = aa; bb = isSig ? (aa + t) : t; break; }
    t -= c;
  }
  int pa = isSig ? 0 : 3;                    // A = Qu : Qc
  int pb = isSig ? 1 : 2;                    // B = Ku : Vu
  const char* Ahg = (const char*)ph + (size_t)pa*1048576;
  const char* Alg = (const char*)pl + (size_t)pa*1048576;
  const char* Bhg = (const char*)ph + (size_t)pb*1048576;
  const char* Blg = (const char*)pl + (size_t)pb*1048576;
  int tid = threadIdx.x, w = tid >> 6, lane = tid & 63;
  int lm = lane & 15, quad = lane >> 4;
  int srow = lane >> 3, scg = (lane & 7) ^ srow;
  int wm = (w & 1)*64, wn = (w >> 1)*64;
  #pragma unroll
  for (int i2 = 0; i2 < 4; ++i2){
    int i = w*4 + i2;
    int rl = i*8 + srow;
    size_t ga = (size_t)(b*2048 + a*128  + rl)*128 + scg*16;
    size_t gb = (size_t)(b*2048 + bb*128 + rl)*128 + scg*16;
    GLDS16(Ahg + ga, sm +         i*1024);
    GLDS16(Alg + ga, sm + 16384 + i*1024);
    GLDS16(Bhg + gb, sm + 32768 + i*1024);
    GLDS16(Blg + gb, sm + 49152 + i*1024);
  }
  __syncthreads();
  f32x4 acc[4][4] = {};
  #pragma unroll
  for (int ks = 0; ks < 2; ++ks){
    bf16x8 bh[4], bl[4];
    #pragma unroll
    for (int n = 0; n < 4; ++n){
      int r = wn + n*16 + lm;
      int off = r*128 + (((ks*4+quad) ^ (r&7))*16);
      bh[n] = *(const bf16x8*)(sm + 32768 + off);
      bl[n] = *(const bf16x8*)(sm + 49152 + off);
    }
    #pragma unroll
    for (int m = 0; m < 4; ++m){
      int r = wm + m*16 + lm;
      int off = r*128 + (((ks*4+quad) ^ (r&7))*16);
      bf16x8 ah = *(const bf16x8*)(sm + off);
      bf16x8 al = *(const bf16x8*)(sm + 16384 + off);
      #pragma unroll
      for (int n = 0; n < 4; ++n){
        acc[m][n] = MFMA16(ah, bh[n], acc[m][n]);
        acc[m][n] = MFMA16(ah, bl[n], acc[m][n]);
        acc[m][n] = MFMA16(al, bh[n], acc[m][n]);
      }
    }
  }
  __syncthreads();
  _Float16* Tt = (_Float16*)sm;              // 128x128 fp16 tile (32 KB)
  #pragma unroll
  for (int m = 0; m < 4; ++m){
    #pragma unroll
    for (int n = 0; n < 4; ++n){
      #pragma unroll
      for (int e = 0; e < 4; ++e){
        int il = wm + m*16 + quad*4 + e;
        int jl = wn + n*16 + lm;
        int gi = a*128 + il, gj = bb*128 + jl;
        float v = acc[m][n][e] * 0.125f;
        float outv;
        if (!isSig) outv = (gj <= gi) ? v : 0.0f;
        else        outv = (gj >  gi) ? (1.0f/(1.0f + __expf(-v))) : 0.0f;
        Tt[il*128 + jl] = (_Float16)outv;
      }
    }
  }
  __syncthreads();
  _Float16* outp = (isSig ? sg : t1) + (size_t)b*4194304;
  #pragma unroll
  for (int r = 0; r < 8; ++r){
    int lrow = w*32 + r*4 + (lane >> 4);
    int c16 = lane & 15;
    f32x4 vv = *(const f32x4*)(sm + lrow*256 + c16*16);
    *(f32x4*)((char*)(outp + (size_t)(a*128 + lrow)*2048 + bb*128) + c16*16) = vv;
  }
}

// ---------------- P3: S_u = term1 @ sig^T (fp16 MFMA, tri-tiled) + fused S_c -> logits fp16 ----------------
__global__ __launch_bounds__(256,2) void k_p3(
    const unsigned short* __restrict__ ph, const unsigned short* __restrict__ pl,
    const _Float16* __restrict__ t1, const _Float16* __restrict__ sg,
    _Float16* __restrict__ lg){
  __shared__ __align__(16) char sm[32768];   // Af 16K | Bf 16K; reused for epilogue
  int b = blockIdx.y;
  int v = blockIdx.x, I = 0, K = 0;
  #pragma unroll 1
  for (int d = 15; d >= 0; --d){             // longest (I-K) first
    int nd = 16 - d;
    if (v < nd){ I = d + v; K = v; break; }
    v -= nd;
  }
  int tid = threadIdx.x, w = tid >> 6, lane = tid & 63;
  int lm = lane & 15, quad = lane >> 4;
  size_t mat = (size_t)b * 4194304;
  const char* Ag = (const char*)(t1 + mat);
  const char* Bg = (const char*)(sg + mat);
  int srow = lane >> 3, scg = (lane & 7) ^ srow;
  int wm = (w & 1)*64, wn = (w >> 1)*64;
  f32x4 su[4][4] = {};
  for (int j64 = 2*K; j64 <= 2*I + 1; ++j64){
    __syncthreads();
    size_t colb = (size_t)j64*128 + scg*16;
    #pragma unroll
    for (int i2 = 0; i2 < 4; ++i2){
      int i = w*4 + i2;
      int rl = i*8 + srow;
      GLDS16(Ag + (size_t)(I*128 + rl)*4096 + colb, sm +         i*1024);
      GLDS16(Bg + (size_t)(K*128 + rl)*4096 + colb, sm + 16384 + i*1024);
    }
    __syncthreads();
    #pragma unroll
    for (int ks = 0; ks < 2; ++ks){
      f16x8 bf[4];
      #pragma unroll
      for (int n = 0; n < 4; ++n){
        int r = wn + n*16 + lm;
        bf[n] = *(const f16x8*)(sm + 16384 + r*128 + (((ks*4+quad) ^ (r&7))*16));
      }
      #pragma unroll
      for (int m = 0; m < 4; ++m){
        int r = wm + m*16 + lm;
        f16x8 af = *(const f16x8*)(sm + r*128 + (((ks*4+quad) ^ (r&7))*16));
        #pragma unroll
        for (int n = 0; n < 4; ++n)
          su[m][n] = MFMAF16(af, bf[n], su[m][n]);
      }
    }
  }
  // fused S_c = Qc @ Kc^T (split bf16 from prebuilt h/l)
  const char* Qh = (const char*)ph + (size_t)3*1048576;
  const char* Ql = (const char*)pl + (size_t)3*1048576;
  const char* Kh = (const char*)ph + (size_t)4*1048576;
  const char* Kl = (const char*)pl + (size_t)4*1048576;
  f32x4 sc[4][4] = {};
  #pragma unroll
  for (int ks = 0; ks < 2; ++ks){
    bf16x8 kh[4], kl[4];
    #pragma unroll
    for (int n = 0; n < 4; ++n){
      size_t off = (size_t)(b*2048 + K*128 + wn + n*16 + lm)*128 + (ks*32 + quad*8)*2;
      kh[n] = *(const bf16x8*)(Kh + off);
      kl[n] = *(const bf16x8*)(Kl + off);
    }
    #pragma unroll
    for (int m = 0; m < 4; ++m){
      size_t off = (size_t)(b*2048 + I*128 + wm + m*16 + lm)*128 + (ks*32 + quad*8)*2;
      bf16x8 ah = *(const bf16x8*)(Qh + off);
      bf16x8 al = *(const bf16x8*)(Ql + off);
      #pragma unroll
      for (int n = 0; n < 4; ++n){
        sc[m][n] = MFMA16(ah, kh[n], sc[m][n]);
        sc[m][n] = MFMA16(ah, kl[n], sc[m][n]);
        sc[m][n] = MFMA16(al, kh[n], sc[m][n]);
      }
    }
  }
  __syncthreads();
  _Float16* Tt = (_Float16*)sm;              // 128x128 fp16 logits tile
  #pragma unroll
  for (int m = 0; m < 4; ++m){
    #pragma unroll
    for (int n = 0; n < 4; ++n){
      #pragma unroll
      for (int e = 0; e < 4; ++e){
        int il = wm + m*16 + quad*4 + e;
        int jl = wn + n*16 + lm;
        float xv = su[m][n][e];
        float sgm = 1.0f/(1.0f + __expf(-xv));
        Tt[il*128 + jl] = (_Float16)(sc[m][n][e]*0.125f - xv*sgm);
      }
    }
  }
  __syncthreads();
  _Float16* lgb = lg + mat;
  #pragma unroll
  for (int r = 0; r < 8; ++r){
    int lrow = w*32 + r*4 + (lane >> 4);
    int c16 = lane & 15;
    f32x4 vv = *(const f32x4*)(sm + lrow*256 + c16*16);
    *(f32x4*)((char*)(lgb + (size_t)(I*128 + lrow)*2048 + K*128) + c16*16) = vv;
  }
}

// ---------------- P4a: per-row causal max + sum-exp (one wave per row) ----------------
__global__ __launch_bounds__(256) void k_p4a(const _Float16* __restrict__ lg,
    float* __restrict__ mrow, float* __restrict__ zrow){
  int b = blockIdx.y;
  int wid = blockIdx.x*4 + (threadIdx.x >> 6);
  int row = 2047 - wid;                        // longest rows first
  int lane = threadIdx.x & 63;
  const _Float16* lr = lg + (size_t)b*4194304u + (size_t)row*2048;
  float m_r = -1.0e30f, s_r = 0.0f;
  int nch = (row >> 9) + 1;
  for (int it = 0; it < nch; ++it){
    int base = it*512 + lane*8;
    if (base <= row){
      f16x8 vv = *(const f16x8*)(lr + base);
      float xs[8]; float mc = -1.0e30f;
      #pragma unroll
      for (int e = 0; e < 8; ++e){
        xs[e] = (base + e <= row) ? (float)vv[e] : -1.0e30f;
        mc = fmaxf(mc, xs[e]);
      }
      float mm = fmaxf(m_r, mc);
      float s = 0.0f;
      #pragma unroll
      for (int e = 0; e < 8; ++e)
        if (xs[e] > -1.0e29f) s += __expf(xs[e] - mm);
      s_r = (m_r > -1.0e29f ? s_r*__expf(m_r - mm) : 0.0f) + s;
      m_r = mm;
    }
  }
  #pragma unroll
  for (int off = 32; off; off >>= 1){
    float mo = __shfl_xor(m_r, off);
    float so = __shfl_xor(s_r, off);
    float mm = fmaxf(m_r, mo);
    float s = 0.0f;
    if (m_r > -1.0e29f) s += s_r*__expf(m_r - mm);
    if (mo  > -1.0e29f) s += so *__expf(mo  - mm);
    m_r = mm; s_r = s;
  }
  if (lane == 0){
    mrow[b*2048 + row] = m_r;
    zrow[b*2048 + row] = s_r;
  }
}

// ---------------- P4b: out = softmax(P) @ V_c — 16-row band/block, kt split across 4 waves ----------------
__global__ __launch_bounds__(256) void k_p4b(const _Float16* __restrict__ lg,
    const _Float16* __restrict__ vct,
    const float* __restrict__ mrow, const float* __restrict__ zrow,
    float* __restrict__ out){
  __shared__ __align__(16) float Ot[4][16][64];
  __shared__ __align__(16) _Float16 Ls[4][16][64];
  int b = blockIdx.y;
  int band = 127 - blockIdx.x;                 // longest first
  int r0 = band*16;
  int tid = threadIdx.x, w = tid >> 6, lane = tid & 63;
  int lm = lane & 15, quad = lane >> 4;
  const _Float16* lgb = lg + (size_t)b*4194304u;
  const _Float16* vb = vct + (size_t)b*131072;
  int arow = r0 + lm;
  float mv = mrow[b*2048 + arow];
  int nkt = ((r0 + 15) >> 6) + 1;
  int fc = (r0 + 1) >> 6;
  int sr = lane >> 2, sc4 = (lane & 3)*16;
  f32x4 acc[4] = {};
  for (int kt = w; kt < nkt; kt += 4){
    const _Float16* src = lgb + (size_t)(r0 + sr)*2048 + kt*64 + sc4;
    *(f16x8*)&Ls[w][sr][sc4]     = *(const f16x8*)src;
    *(f16x8*)&Ls[w][sr][sc4 + 8] = *(const f16x8*)(src + 8);
    bool full = kt < fc;
    #pragma unroll
    for (int ks = 0; ks < 2; ++ks){
      int jbase = kt*64 + ks*32 + quad*8;
      f16x8 Lv = *(const f16x8*)&Ls[w][lm][ks*32 + quad*8];
      f16x8 af;
      #pragma unroll
      for (int e = 0; e < 8; ++e){
        float p = __expf((float)Lv[e] - mv);
        if (!full && (jbase + e > arow)) p = 0.0f;
        af[e] = (_Float16)p;
      }
      #pragma unroll
      for (int n = 0; n < 4; ++n){
        f16x8 bv = *(const f16x8*)(vb + (size_t)(n*16 + lm)*2048 + jbase);
        acc[n] = MFMAF16(af, bv, acc[n]);
      }
    }
  }
  #pragma unroll
  for (int n = 0; n < 4; ++n)
    #pragma unroll
    for (int e = 0; e < 4; ++e)
      Ot[w][quad*4 + e][n*16 + lm] = acc[n][e];
  __syncthreads();
  int row = tid >> 4, c4 = (tid & 15)*4;
  f32x4 s = *(const f32x4*)&Ot[0][row][c4];
  #pragma unroll
  for (int ww = 1; ww < 4; ++ww){
    f32x4 t = *(const f32x4*)&Ot[ww][row][c4];
    s[0]+=t[0]; s[1]+=t[1]; s[2]+=t[2]; s[3]+=t[3];
  }
  float z = zrow[b*2048 + r0 + row];
  f32x4 o = { s[0]/z, s[1]/z, s[2]/z, s[3]/z };
  *(f32x4*)(out + ((size_t)b*2048 + r0 + row)*64 + c4) = o;
}

// ---------------- workspace layout (bytes) ----------------
static const size_t OFF_PROJ  = 0;           // 6 x 8192x64 f32   = 12,582,912
static const size_t OFF_WTH   = 12582912;    // 6 x 64x1024 bf16 (reused as mrow after proj)
static const size_t OFF_WTL   = 13369344;    //                  (reused as zrow after proj)
static const size_t OFF_PROJH = 14155776;    // 6 x 8192x64 bf16  =  6,291,456
static const size_t OFF_PROJL = 20447232;    //                      6,291,456
static const size_t OFF_VCT   = 26738688;    // 4 x 64x2048 f16   =  1,048,576
static const size_t OFF_T1    = 27787264;    // 4 x 2048^2 f16    = 33,554,432
static const size_t OFF_SG    = 61341696;    //                     33,554,432
static const size_t OFF_LG    = 94896128;    //                     33,554,432
// total = 128,450,560 bytes

extern "C" void kernel_launch(void* const* d_in, const int* in_sizes, int n_in,
                              void* d_out, int out_size, void* d_ws, size_t ws_size,
                              hipStream_t stream){
  (void)in_sizes; (void)n_in; (void)out_size; (void)ws_size;
  const float* x = (const float*)d_in[0];
  char* ws = (char*)d_ws;
  float*          proj  = (float*)(ws + OFF_PROJ);
  unsigned short* wth   = (unsigned short*)(ws + OFF_WTH);
  unsigned short* wtl   = (unsigned short*)(ws + OFF_WTL);
  unsigned short* projh = (unsigned short*)(ws + OFF_PROJH);
  unsigned short* projl = (unsigned short*)(ws + OFF_PROJL);
  _Float16*       vct   = (_Float16*)(ws + OFF_VCT);
  _Float16*       t1    = (_Float16*)(ws + OFF_T1);
  _Float16*       sg    = (_Float16*)(ws + OFF_SG);
  _Float16*       lg    = (_Float16*)(ws + OFF_LG);
  float*          mbuf  = (float*)(ws + OFF_WTH);   // weights dead after k_proj
  float*          zbuf  = (float*)(ws + OFF_WTL);

  k_wt  <<<dim3(256,6), 256, 0, stream>>>((const float*)d_in[1], (const float*)d_in[2],
                                          (const float*)d_in[3], (const float*)d_in[4],
                                          (const float*)d_in[5], (const float*)d_in[6], wth, wtl);
  k_proj<<<dim3(384),   256, 0, stream>>>(x, wth, wtl, proj, projh, projl);
  k_vct <<<dim3(32,4),  256, 0, stream>>>(proj, vct);
  k_p2  <<<dim3(272,4), 256, 0, stream>>>(projh, projl, t1, sg);
  k_p3  <<<dim3(136,4), 256, 0, stream>>>(projh, projl, t1, sg, lg);
  k_p4a <<<dim3(512,4), 256, 0, stream>>>(lg, mbuf, zbuf);
  k_p4b <<<dim3(128,4), 256, 0, stream>>>(lg, vct, mbuf, zbuf, (float*)d_out);
}

// Round 7
// 227.923 us; speedup vs baseline: 2.9203x; 1.0204x over previous
//
#include <hip/hip_runtime.h>
#include <hip/hip_bf16.h>

// B=4, S=2048, D=1024, DH=64. Inputs/outputs are FLOAT32 (per reference).
typedef short bf16x8 __attribute__((ext_vector_type(8)));
typedef float f32x4  __attribute__((ext_vector_type(4)));
typedef _Float16 f16x4 __attribute__((ext_vector_type(4)));
typedef _Float16 f16x8 __attribute__((ext_vector_type(8)));

#define MFMA16(a,b,c)  __builtin_amdgcn_mfma_f32_16x16x32_bf16((a),(b),(c),0,0,0)
#define MFMAF16(a,b,c) __builtin_amdgcn_mfma_f32_16x16x32_f16((a),(b),(c),0,0,0)

// async global->LDS: 16B per lane, lane i lands at lds_base + i*16
#define GLDS16(g,l) __builtin_amdgcn_global_load_lds( \
    (const __attribute__((address_space(1))) void*)(g), \
    (__attribute__((address_space(3))) void*)(l), 16, 0, 0)

__device__ __forceinline__ short f2bf(float f){
  union { float f; unsigned u; } v; v.f = f;
  unsigned r = v.u + 0x7fffu + ((v.u >> 16) & 1u);
  return (short)(r >> 16);
}
__device__ __forceinline__ float bf2f(short h){
  union { unsigned u; float f; } v; v.u = ((unsigned)(unsigned short)h) << 16;
  return v.f;
}
__device__ __forceinline__ void split8v(f32x4 a, f32x4 b, bf16x8& h, bf16x8& l){
  float t[8] = {a[0],a[1],a[2],a[3],b[0],b[1],b[2],b[3]};
  #pragma unroll
  for (int e = 0; e < 8; ++e){
    short hs = f2bf(t[e]);
    h[e] = hs;
    l[e] = f2bf(t[e] - bf2f(hs));
  }
}

// ---------------- P0a: transpose+split 6 weights (1024x64 f32 -> 64x1024 bf16 hi/lo) ----------------
__global__ void k_wt(const float* w0, const float* w1, const float* w2,
                     const float* w3, const float* w4, const float* w5,
                     unsigned short* __restrict__ wth, unsigned short* __restrict__ wtl){
  int p = blockIdx.y;
  const float* wp = p==0?w0:p==1?w1:p==2?w2:p==3?w3:p==4?w4:w5;
  int idx = blockIdx.x*256 + threadIdx.x;     // [0,65536)
  int n = idx >> 10, k = idx & 1023;
  float v = wp[k*64 + n];
  short hs = f2bf(v);
  wth[(size_t)p*65536 + n*1024 + k] = (unsigned short)hs;
  wtl[(size_t)p*65536 + n*1024 + k] = (unsigned short)f2bf(v - bf2f(hs));
}

// ---------------- P0b: x f32 -> xh/xl bf16 (once) ----------------
__global__ void k_xsplit(const float* __restrict__ x,
                         unsigned short* __restrict__ xh, unsigned short* __restrict__ xl){
  size_t i = ((size_t)blockIdx.x*256 + threadIdx.x)*8;   // 8.39M elems / 8
  f32x4 a = *(const f32x4*)(x + i);
  f32x4 b = *(const f32x4*)(x + i + 4);
  bf16x8 h, l;
  split8v(a, b, h, l);
  *(bf16x8*)(xh + i) = h;
  *(bf16x8*)(xl + i) = l;
}

// ---------------- P1: all 6 projections, fully DMA-staged ----------------
// grid: 64 row-blocks x 6 p (p inner for x L2/L3 reuse). 256 thr.
__global__ __launch_bounds__(256) void k_proj(
    const unsigned short* __restrict__ xh, const unsigned short* __restrict__ xl,
    const unsigned short* __restrict__ wth, const unsigned short* __restrict__ wtl,
    float* __restrict__ proj,
    unsigned short* __restrict__ projh, unsigned short* __restrict__ projl){
  __shared__ __align__(16) char sm[49152];   // xh 16K | xl 16K | wh 8K | wl 8K
  int blk = blockIdx.x;
  int rb = blk/6, p = blk - rb*6;
  int tid = threadIdx.x, w = tid >> 6, lane = tid & 63;
  int lm = lane & 15, quad = lane >> 4;
  int srow = lane >> 3, scg = (lane & 7) ^ srow;
  const char* xhg = (const char*)xh;
  const char* xlg = (const char*)xl;
  const char* wthp = (const char*)wth + (size_t)p*131072;
  const char* wtlp = (const char*)wtl + (size_t)p*131072;
  int wm = w*32;
  f32x4 acc[2][4] = {};
  for (int k0 = 0; k0 < 1024; k0 += 64){
    __syncthreads();
    size_t cb = (size_t)k0*2 + scg*16;
    // x tile: 128 rows x 64 k, hi/lo (16 instr per buffer)
    #pragma unroll
    for (int i2 = 0; i2 < 4; ++i2){
      int i = w*4 + i2;
      size_t g = (size_t)(rb*128 + i*8 + srow)*2048 + cb;
      GLDS16(xhg + g, sm +         i*1024);
      GLDS16(xlg + g, sm + 16384 + i*1024);
    }
    // w tile: 64 c-rows x 64 k, hi/lo (8 instr per buffer)
    #pragma unroll
    for (int i2 = 0; i2 < 2; ++i2){
      int i = w*2 + i2;
      size_t g = (size_t)(i*8 + srow)*2048 + cb;
      GLDS16(wthp + g, sm + 32768 + i*1024);
      GLDS16(wtlp + g, sm + 40960 + i*1024);
    }
    __syncthreads();
    #pragma unroll
    for (int ks = 0; ks < 2; ++ks){
      bf16x8 bh[4], bl[4];
      #pragma unroll
      for (int n = 0; n < 4; ++n){
        int r = n*16 + lm;
        int off = r*128 + (((ks*4+quad) ^ (r&7))*16);
        bh[n] = *(const bf16x8*)(sm + 32768 + off);
        bl[n] = *(const bf16x8*)(sm + 40960 + off);
      }
      #pragma unroll
      for (int m = 0; m < 2; ++m){
        int r = wm + m*16 + lm;
        int off = r*128 + (((ks*4+quad) ^ (r&7))*16);
        bf16x8 ah = *(const bf16x8*)(sm + off);
        bf16x8 al = *(const bf16x8*)(sm + 16384 + off);
        #pragma unroll
        for (int n = 0; n < 4; ++n){
          acc[m][n] = MFMA16(ah, bh[n], acc[m][n]);
          acc[m][n] = MFMA16(ah, bl[n], acc[m][n]);
          acc[m][n] = MFMA16(al, bh[n], acc[m][n]);
        }
      }
    }
  }
  if (p == 5){
    float* op = proj + (size_t)p*524288;
    #pragma unroll
    for (int m = 0; m < 2; ++m)
      #pragma unroll
      for (int n = 0; n < 4; ++n)
        #pragma unroll
        for (int e = 0; e < 4; ++e){
          int r = rb*128 + wm + m*16 + quad*4 + e;
          op[(size_t)r*64 + n*16 + lm] = acc[m][n][e];
        }
  } else {
    unsigned short* oph = projh + (size_t)p*524288;
    unsigned short* opl = projl + (size_t)p*524288;
    #pragma unroll
    for (int m = 0; m < 2; ++m)
      #pragma unroll
      for (int n = 0; n < 4; ++n)
        #pragma unroll
        for (int e = 0; e < 4; ++e){
          int r = rb*128 + wm + m*16 + quad*4 + e;
          float f = acc[m][n][e];
          short hs = f2bf(f);
          oph[(size_t)r*64 + n*16 + lm] = (unsigned short)hs;
          opl[(size_t)r*64 + n*16 + lm] = (unsigned short)f2bf(f - bf2f(hs));
        }
  }
}

// ---------------- P1b: V_c f32 -> V_c^T fp16 (per batch 64 x 2048) ----------------
__global__ void k_vct(const float* __restrict__ proj, _Float16* __restrict__ vct){
  __shared__ float T[64][65];
  int b = blockIdx.y, st = blockIdx.x;       // s-tile [0,32)
  int tid = threadIdx.x;
  const float* vc = proj + 5*524288 + (size_t)b*131072;
  int sloc = tid >> 2, cp = (tid & 3)*16;
  #pragma unroll
  for (int j = 0; j < 4; ++j){
    f32x4 v = *(const f32x4*)(vc + (size_t)(st*64 + sloc)*64 + cp + j*4);
    #pragma unroll
    for (int e = 0; e < 4; ++e) T[sloc][cp + j*4 + e] = v[e];
  }
  __syncthreads();
  int d = tid >> 2, sp = (tid & 3)*16;
  f16x8 h0, h1;
  #pragma unroll
  for (int j = 0; j < 8; ++j) h0[j] = (_Float16)T[sp + j][d];
  #pragma unroll
  for (int j = 0; j < 8; ++j) h1[j] = (_Float16)T[sp + 8 + j][d];
  size_t o = (size_t)b*131072 + (size_t)d*2048 + st*64 + sp;
  *(f16x8*)(vct + o) = h0; *(f16x8*)(vct + o + 8) = h1;
}

// ---------------- P2: term1 / sigmoid-gate tiles, LDS-staged split GEMM -> fp16 ----------------
__global__ __launch_bounds__(256,2) void k_p2(
    const unsigned short* __restrict__ ph, const unsigned short* __restrict__ pl,
    _Float16* __restrict__ t1, _Float16* __restrict__ sg){
  __shared__ __align__(16) char sm[65536];   // Ah | Al | Bh | Bl (16K each); reused for epilogue
  int b = blockIdx.y;
  int t = blockIdx.x;                        // [0,272): 136 term1 tiles + 136 sig tiles
  bool isSig = t >= 136;
  if (isSig) t -= 136;
  int a = 0, bb = 0;
  #pragma unroll 1
  for (int aa = 0; aa < 16; ++aa){
    int c = isSig ? (16 - aa) : (aa + 1);
    if (t < c){ a = aa; bb = isSig ? (aa + t) : t; break; }
    t -= c;
  }
  int pa = isSig ? 0 : 3;                    // A = Qu : Qc
  int pb = isSig ? 1 : 2;                    // B = Ku : Vu
  const char* Ahg = (const char*)ph + (size_t)pa*1048576;
  const char* Alg = (const char*)pl + (size_t)pa*1048576;
  const char* Bhg = (const char*)ph + (size_t)pb*1048576;
  const char* Blg = (const char*)pl + (size_t)pb*1048576;
  int tid = threadIdx.x, w = tid >> 6, lane = tid & 63;
  int lm = lane & 15, quad = lane >> 4;
  int srow = lane >> 3, scg = (lane & 7) ^ srow;
  int wm = (w & 1)*64, wn = (w >> 1)*64;
  #pragma unroll
  for (int i2 = 0; i2 < 4; ++i2){
    int i = w*4 + i2;
    int rl = i*8 + srow;
    size_t ga = (size_t)(b*2048 + a*128  + rl)*128 + scg*16;
    size_t gb = (size_t)(b*2048 + bb*128 + rl)*128 + scg*16;
    GLDS16(Ahg + ga, sm +         i*1024);
    GLDS16(Alg + ga, sm + 16384 + i*1024);
    GLDS16(Bhg + gb, sm + 32768 + i*1024);
    GLDS16(Blg + gb, sm + 49152 + i*1024);
  }
  __syncthreads();
  f32x4 acc[4][4] = {};
  #pragma unroll
  for (int ks = 0; ks < 2; ++ks){
    bf16x8 bh[4], bl[4];
    #pragma unroll
    for (int n = 0; n < 4; ++n){
      int r = wn + n*16 + lm;
      int off = r*128 + (((ks*4+quad) ^ (r&7))*16);
      bh[n] = *(const bf16x8*)(sm + 32768 + off);
      bl[n] = *(const bf16x8*)(sm + 49152 + off);
    }
    #pragma unroll
    for (int m = 0; m < 4; ++m){
      int r = wm + m*16 + lm;
      int off = r*128 + (((ks*4+quad) ^ (r&7))*16);
      bf16x8 ah = *(const bf16x8*)(sm + off);
      bf16x8 al = *(const bf16x8*)(sm + 16384 + off);
      #pragma unroll
      for (int n = 0; n < 4; ++n){
        acc[m][n] = MFMA16(ah, bh[n], acc[m][n]);
        acc[m][n] = MFMA16(ah, bl[n], acc[m][n]);
        acc[m][n] = MFMA16(al, bh[n], acc[m][n]);
      }
    }
  }
  __syncthreads();
  _Float16* Tt = (_Float16*)sm;              // 128x128 fp16 tile (32 KB)
  #pragma unroll
  for (int m = 0; m < 4; ++m){
    #pragma unroll
    for (int n = 0; n < 4; ++n){
      #pragma unroll
      for (int e = 0; e < 4; ++e){
        int il = wm + m*16 + quad*4 + e;
        int jl = wn + n*16 + lm;
        int gi = a*128 + il, gj = bb*128 + jl;
        float v = acc[m][n][e] * 0.125f;
        float outv;
        if (!isSig) outv = (gj <= gi) ? v : 0.0f;
        else        outv = (gj >  gi) ? (1.0f/(1.0f + __expf(-v))) : 0.0f;
        Tt[il*128 + jl] = (_Float16)outv;
      }
    }
  }
  __syncthreads();
  _Float16* outp = (isSig ? sg : t1) + (size_t)b*4194304;
  #pragma unroll
  for (int r = 0; r < 8; ++r){
    int lrow = w*32 + r*4 + (lane >> 4);
    int c16 = lane & 15;
    f32x4 vv = *(const f32x4*)(sm + lrow*256 + c16*16);
    *(f32x4*)((char*)(outp + (size_t)(a*128 + lrow)*2048 + bb*128) + c16*16) = vv;
  }
}

// ---------------- P3: S_u = term1 @ sig^T (fp16 MFMA, tri-tiled) + fused S_c -> logits fp16 ----------------
__global__ __launch_bounds__(256,2) void k_p3(
    const unsigned short* __restrict__ ph, const unsigned short* __restrict__ pl,
    const _Float16* __restrict__ t1, const _Float16* __restrict__ sg,
    _Float16* __restrict__ lg){
  __shared__ __align__(16) char sm[32768];   // Af 16K | Bf 16K; reused for epilogue
  int b = blockIdx.y;
  int v = blockIdx.x, I = 0, K = 0;
  #pragma unroll 1
  for (int d = 15; d >= 0; --d){             // longest (I-K) first
    int nd = 16 - d;
    if (v < nd){ I = d + v; K = v; break; }
    v -= nd;
  }
  int tid = threadIdx.x, w = tid >> 6, lane = tid & 63;
  int lm = lane & 15, quad = lane >> 4;
  size_t mat = (size_t)b * 4194304;
  const char* Ag = (const char*)(t1 + mat);
  const char* Bg = (const char*)(sg + mat);
  int srow = lane >> 3, scg = (lane & 7) ^ srow;
  int wm = (w & 1)*64, wn = (w >> 1)*64;
  f32x4 su[4][4] = {};
  for (int j64 = 2*K; j64 <= 2*I + 1; ++j64){
    __syncthreads();
    size_t colb = (size_t)j64*128 + scg*16;
    #pragma unroll
    for (int i2 = 0; i2 < 4; ++i2){
      int i = w*4 + i2;
      int rl = i*8 + srow;
      GLDS16(Ag + (size_t)(I*128 + rl)*4096 + colb, sm +         i*1024);
      GLDS16(Bg + (size_t)(K*128 + rl)*4096 + colb, sm + 16384 + i*1024);
    }
    __syncthreads();
    #pragma unroll
    for (int ks = 0; ks < 2; ++ks){
      f16x8 bf[4];
      #pragma unroll
      for (int n = 0; n < 4; ++n){
        int r = wn + n*16 + lm;
        bf[n] = *(const f16x8*)(sm + 16384 + r*128 + (((ks*4+quad) ^ (r&7))*16));
      }
      #pragma unroll
      for (int m = 0; m < 4; ++m){
        int r = wm + m*16 + lm;
        f16x8 af = *(const f16x8*)(sm + r*128 + (((ks*4+quad) ^ (r&7))*16));
        #pragma unroll
        for (int n = 0; n < 4; ++n)
          su[m][n] = MFMAF16(af, bf[n], su[m][n]);
      }
    }
  }
  // fused S_c = Qc @ Kc^T (split bf16 from prebuilt h/l)
  const char* Qh = (const char*)ph + (size_t)3*1048576;
  const char* Ql = (const char*)pl + (size_t)3*1048576;
  const char* Kh = (const char*)ph + (size_t)4*1048576;
  const char* Kl = (const char*)pl + (size_t)4*1048576;
  f32x4 sc[4][4] = {};
  #pragma unroll
  for (int ks = 0; ks < 2; ++ks){
    bf16x8 kh[4], kl[4];
    #pragma unroll
    for (int n = 0; n < 4; ++n){
      size_t off = (size_t)(b*2048 + K*128 + wn + n*16 + lm)*128 + (ks*32 + quad*8)*2;
      kh[n] = *(const bf16x8*)(Kh + off);
      kl[n] = *(const bf16x8*)(Kl + off);
    }
    #pragma unroll
    for (int m = 0; m < 4; ++m){
      size_t off = (size_t)(b*2048 + I*128 + wm + m*16 + lm)*128 + (ks*32 + quad*8)*2;
      bf16x8 ah = *(const bf16x8*)(Qh + off);
      bf16x8 al = *(const bf16x8*)(Ql + off);
      #pragma unroll
      for (int n = 0; n < 4; ++n){
        sc[m][n] = MFMA16(ah, kh[n], sc[m][n]);
        sc[m][n] = MFMA16(ah, kl[n], sc[m][n]);
        sc[m][n] = MFMA16(al, kh[n], sc[m][n]);
      }
    }
  }
  __syncthreads();
  _Float16* Tt = (_Float16*)sm;              // 128x128 fp16 logits tile
  #pragma unroll
  for (int m = 0; m < 4; ++m){
    #pragma unroll
    for (int n = 0; n < 4; ++n){
      #pragma unroll
      for (int e = 0; e < 4; ++e){
        int il = wm + m*16 + quad*4 + e;
        int jl = wn + n*16 + lm;
        float xv = su[m][n][e];
        float sgm = 1.0f/(1.0f + __expf(-xv));
        Tt[il*128 + jl] = (_Float16)(sc[m][n][e]*0.125f - xv*sgm);
      }
    }
  }
  __syncthreads();
  _Float16* lgb = lg + mat;
  #pragma unroll
  for (int r = 0; r < 8; ++r){
    int lrow = w*32 + r*4 + (lane >> 4);
    int c16 = lane & 15;
    f32x4 vv = *(const f32x4*)(sm + lrow*256 + c16*16);
    *(f32x4*)((char*)(lgb + (size_t)(I*128 + lrow)*2048 + K*128) + c16*16) = vv;
  }
}

// ---------------- P4a: per-row causal max + sum-exp (one wave per row) ----------------
__global__ __launch_bounds__(256) void k_p4a(const _Float16* __restrict__ lg,
    float* __restrict__ mrow, float* __restrict__ zrow){
  int b = blockIdx.y;
  int wid = blockIdx.x*4 + (threadIdx.x >> 6);
  int row = 2047 - wid;                        // longest rows first
  int lane = threadIdx.x & 63;
  const _Float16* lr = lg + (size_t)b*4194304u + (size_t)row*2048;
  float m_r = -1.0e30f, s_r = 0.0f;
  int nch = (row >> 9) + 1;
  for (int it = 0; it < nch; ++it){
    int base = it*512 + lane*8;
    if (base <= row){
      f16x8 vv = *(const f16x8*)(lr + base);
      float xs[8]; float mc = -1.0e30f;
      #pragma unroll
      for (int e = 0; e < 8; ++e){
        xs[e] = (base + e <= row) ? (float)vv[e] : -1.0e30f;
        mc = fmaxf(mc, xs[e]);
      }
      float mm = fmaxf(m_r, mc);
      float s = 0.0f;
      #pragma unroll
      for (int e = 0; e < 8; ++e)
        if (xs[e] > -1.0e29f) s += __expf(xs[e] - mm);
      s_r = (m_r > -1.0e29f ? s_r*__expf(m_r - mm) : 0.0f) + s;
      m_r = mm;
    }
  }
  #pragma unroll
  for (int off = 32; off; off >>= 1){
    float mo = __shfl_xor(m_r, off);
    float so = __shfl_xor(s_r, off);
    float mm = fmaxf(m_r, mo);
    float s = 0.0f;
    if (m_r > -1.0e29f) s += s_r*__expf(m_r - mm);
    if (mo  > -1.0e29f) s += so *__expf(mo  - mm);
    m_r = mm; s_r = s;
  }
  if (lane == 0){
    mrow[b*2048 + row] = m_r;
    zrow[b*2048 + row] = s_r;
  }
}

// ---------------- P4b: out = softmax(P) @ V_c — 16-row band/block, kt split across 4 waves ----------------
__global__ __launch_bounds__(256) void k_p4b(const _Float16* __restrict__ lg,
    const _Float16* __restrict__ vct,
    const float* __restrict__ mrow, const float* __restrict__ zrow,
    float* __restrict__ out){
  __shared__ __align__(16) float Ot[4][16][64];
  __shared__ __align__(16) _Float16 Ls[4][16][64];
  int b = blockIdx.y;
  int band = 127 - blockIdx.x;                 // longest first
  int r0 = band*16;
  int tid = threadIdx.x, w = tid >> 6, lane = tid & 63;
  int lm = lane & 15, quad = lane >> 4;
  const _Float16* lgb = lg + (size_t)b*4194304u;
  const _Float16* vb = vct + (size_t)b*131072;
  int arow = r0 + lm;
  float mv = mrow[b*2048 + arow];
  int nkt = ((r0 + 15) >> 6) + 1;
  int fc = (r0 + 1) >> 6;
  int sr = lane >> 2, sc4 = (lane & 3)*16;
  f32x4 acc[4] = {};
  for (int kt = w; kt < nkt; kt += 4){
    const _Float16* src = lgb + (size_t)(r0 + sr)*2048 + kt*64 + sc4;
    *(f16x8*)&Ls[w][sr][sc4]     = *(const f16x8*)src;
    *(f16x8*)&Ls[w][sr][sc4 + 8] = *(const f16x8*)(src + 8);
    bool full = kt < fc;
    #pragma unroll
    for (int ks = 0; ks < 2; ++ks){
      int jbase = kt*64 + ks*32 + quad*8;
      f16x8 Lv = *(const f16x8*)&Ls[w][lm][ks*32 + quad*8];
      f16x8 af;
      #pragma unroll
      for (int e = 0; e < 8; ++e){
        float p = __expf((float)Lv[e] - mv);
        if (!full && (jbase + e > arow)) p = 0.0f;
        af[e] = (_Float16)p;
      }
      #pragma unroll
      for (int n = 0; n < 4; ++n){
        f16x8 bv = *(const f16x8*)(vb + (size_t)(n*16 + lm)*2048 + jbase);
        acc[n] = MFMAF16(af, bv, acc[n]);
      }
    }
  }
  #pragma unroll
  for (int n = 0; n < 4; ++n)
    #pragma unroll
    for (int e = 0; e < 4; ++e)
      Ot[w][quad*4 + e][n*16 + lm] = acc[n][e];
  __syncthreads();
  int row = tid >> 4, c4 = (tid & 15)*4;
  f32x4 s = *(const f32x4*)&Ot[0][row][c4];
  #pragma unroll
  for (int ww = 1; ww < 4; ++ww){
    f32x4 t = *(const f32x4*)&Ot[ww][row][c4];
    s[0]+=t[0]; s[1]+=t[1]; s[2]+=t[2]; s[3]+=t[3];
  }
  float z = zrow[b*2048 + r0 + row];
  f32x4 o = { s[0]/z, s[1]/z, s[2]/z, s[3]/z };
  *(f32x4*)(out + ((size_t)b*2048 + r0 + row)*64 + c4) = o;
}

// ---------------- workspace layout (bytes) ----------------
static const size_t OFF_PROJ  = 0;           // 6 x 8192x64 f32 (only p5 written) = 12,582,912
static const size_t OFF_WTH   = 12582912;    // 6 x 64x1024 bf16 (reused as mrow after proj)
static const size_t OFF_WTL   = 13369344;    //                  (reused as zrow after proj)
static const size_t OFF_PROJH = 14155776;    // 6 x 8192x64 bf16  =  6,291,456
static const size_t OFF_PROJL = 20447232;    //                      6,291,456
static const size_t OFF_VCT   = 26738688;    // 4 x 64x2048 f16   =  1,048,576
static const size_t OFF_T1    = 27787264;    // 4 x 2048^2 f16    = 33,554,432
static const size_t OFF_SG    = 61341696;    //                     33,554,432
static const size_t OFF_LG    = 94896128;    //                     33,554,432
static const size_t OFF_XH    = 128450560;   // 8192x1024 bf16    = 16,777,216
static const size_t OFF_XL    = 145227776;   //                     16,777,216
// total = 162,004,992 bytes

extern "C" void kernel_launch(void* const* d_in, const int* in_sizes, int n_in,
                              void* d_out, int out_size, void* d_ws, size_t ws_size,
                              hipStream_t stream){
  (void)in_sizes; (void)n_in; (void)out_size; (void)ws_size;
  const float* x = (const float*)d_in[0];
  char* ws = (char*)d_ws;
  float*          proj  = (float*)(ws + OFF_PROJ);
  unsigned short* wth   = (unsigned short*)(ws + OFF_WTH);
  unsigned short* wtl   = (unsigned short*)(ws + OFF_WTL);
  unsigned short* projh = (unsigned short*)(ws + OFF_PROJH);
  unsigned short* projl = (unsigned short*)(ws + OFF_PROJL);
  _Float16*       vct   = (_Float16*)(ws + OFF_VCT);
  _Float16*       t1    = (_Float16*)(ws + OFF_T1);
  _Float16*       sg    = (_Float16*)(ws + OFF_SG);
  _Float16*       lg    = (_Float16*)(ws + OFF_LG);
  unsigned short* xh    = (unsigned short*)(ws + OFF_XH);
  unsigned short* xl    = (unsigned short*)(ws + OFF_XL);
  float*          mbuf  = (float*)(ws + OFF_WTH);   // weights dead after k_proj
  float*          zbuf  = (float*)(ws + OFF_WTL);

  k_wt    <<<dim3(256,6),  256, 0, stream>>>((const float*)d_in[1], (const float*)d_in[2],
                                             (const float*)d_in[3], (const float*)d_in[4],
                                             (const float*)d_in[5], (const float*)d_in[6], wth, wtl);
  k_xsplit<<<dim3(4096),   256, 0, stream>>>(x, xh, xl);
  k_proj  <<<dim3(384),    256, 0, stream>>>(xh, xl, wth, wtl, proj, projh, projl);
  k_vct   <<<dim3(32,4),   256, 0, stream>>>(proj, vct);
  k_p2    <<<dim3(272,4),  256, 0, stream>>>(projh, projl, t1, sg);
  k_p3    <<<dim3(136,4),  256, 0, stream>>>(projh, projl, t1, sg, lg);
  k_p4a   <<<dim3(512,4),  256, 0, stream>>>(lg, mbuf, zbuf);
  k_p4b   <<<dim3(128,4),  256, 0, stream>>>(lg, vct, mbuf, zbuf, (float*)d_out);
}

// Round 8
// 218.602 us; speedup vs baseline: 3.0449x; 1.0426x over previous
//
#include <hip/hip_runtime.h>
#include <hip/hip_bf16.h>

// B=4, S=2048, D=1024, DH=64. Inputs/outputs are FLOAT32 (per reference).
typedef short bf16x8 __attribute__((ext_vector_type(8)));
typedef float f32x4  __attribute__((ext_vector_type(4)));
typedef _Float16 f16x8 __attribute__((ext_vector_type(8)));

#define MFMA16(a,b,c)  __builtin_amdgcn_mfma_f32_16x16x32_bf16((a),(b),(c),0,0,0)
#define MFMAF16(a,b,c) __builtin_amdgcn_mfma_f32_16x16x32_f16((a),(b),(c),0,0,0)

// async global->LDS: 16B per lane, lane i lands at lds_base + i*16
#define GLDS16(g,l) __builtin_amdgcn_global_load_lds( \
    (const __attribute__((address_space(1))) void*)(g), \
    (__attribute__((address_space(3))) void*)(l), 16, 0, 0)

__device__ __forceinline__ short f2bf(float f){
  union { float f; unsigned u; } v; v.f = f;
  unsigned r = v.u + 0x7fffu + ((v.u >> 16) & 1u);
  return (short)(r >> 16);
}
__device__ __forceinline__ float bf2f(short h){
  union { unsigned u; float f; } v; v.u = ((unsigned)(unsigned short)h) << 16;
  return v.f;
}
__device__ __forceinline__ void split8v(f32x4 a, f32x4 b, bf16x8& h, bf16x8& l){
  float t[8] = {a[0],a[1],a[2],a[3],b[0],b[1],b[2],b[3]};
  #pragma unroll
  for (int e = 0; e < 8; ++e){
    short hs = f2bf(t[e]);
    h[e] = hs;
    l[e] = f2bf(t[e] - bf2f(hs));
  }
}

// ---------------- P0a: transpose+split 6 weights (1024x64 f32 -> 64x1024 bf16 hi/lo) ----------------
__global__ void k_wt(const float* w0, const float* w1, const float* w2,
                     const float* w3, const float* w4, const float* w5,
                     unsigned short* __restrict__ wth, unsigned short* __restrict__ wtl){
  int p = blockIdx.y;
  const float* wp = p==0?w0:p==1?w1:p==2?w2:p==3?w3:p==4?w4:w5;
  int idx = blockIdx.x*256 + threadIdx.x;     // [0,65536)
  int n = idx >> 10, k = idx & 1023;
  float v = wp[k*64 + n];
  short hs = f2bf(v);
  wth[(size_t)p*65536 + n*1024 + k] = (unsigned short)hs;
  wtl[(size_t)p*65536 + n*1024 + k] = (unsigned short)f2bf(v - bf2f(hs));
}

// ---------------- P0b: x f32 -> xh/xl bf16 (once) ----------------
__global__ void k_xsplit(const float* __restrict__ x,
                         unsigned short* __restrict__ xh, unsigned short* __restrict__ xl){
  size_t i = ((size_t)blockIdx.x*256 + threadIdx.x)*8;
  f32x4 a = *(const f32x4*)(x + i);
  f32x4 b = *(const f32x4*)(x + i + 4);
  bf16x8 h, l;
  split8v(a, b, h, l);
  *(bf16x8*)(xh + i) = h;
  *(bf16x8*)(xl + i) = l;
}

// ---------------- P1: projections, 2 p's per block (x re-read 3x not 6x), DMA-staged ----------------
// grid: 128 row-blocks (64 rows) x 3 p-groups, pg fastest. 256 thr.
__global__ __launch_bounds__(256) void k_proj(
    const unsigned short* __restrict__ xh, const unsigned short* __restrict__ xl,
    const unsigned short* __restrict__ wth, const unsigned short* __restrict__ wtl,
    float* __restrict__ proj,
    unsigned short* __restrict__ projh, unsigned short* __restrict__ projl){
  __shared__ __align__(16) char sm[49152];  // xh 8K | xl 8K | w0h 8K | w0l 8K | w1h 8K | w1l 8K
  int blk = blockIdx.x;
  int rb = blk/3, pg = blk - rb*3;
  int tid = threadIdx.x, w = tid >> 6, lane = tid & 63;
  int lm = lane & 15, quad = lane >> 4;
  int srow = lane >> 3, scg = (lane & 7) ^ srow;
  const char* xhg = (const char*)xh;
  const char* xlg = (const char*)xl;
  const char* w0h = (const char*)wth + (size_t)(pg*2  )*131072;
  const char* w0l = (const char*)wtl + (size_t)(pg*2  )*131072;
  const char* w1h = (const char*)wth + (size_t)(pg*2+1)*131072;
  const char* w1l = (const char*)wtl + (size_t)(pg*2+1)*131072;
  f32x4 acc[2][4] = {};
  for (int k0 = 0; k0 < 1024; k0 += 64){
    __syncthreads();
    size_t cb = (size_t)k0*2 + scg*16;
    #pragma unroll
    for (int i2 = 0; i2 < 2; ++i2){
      int i = w*2 + i2;
      size_t gx = (size_t)(rb*64 + i*8 + srow)*2048 + cb;
      size_t gw = (size_t)(i*8 + srow)*2048 + cb;
      GLDS16(xhg + gx, sm +         i*1024);
      GLDS16(xlg + gx, sm +  8192 + i*1024);
      GLDS16(w0h + gw, sm + 16384 + i*1024);
      GLDS16(w0l + gw, sm + 24576 + i*1024);
      GLDS16(w1h + gw, sm + 32768 + i*1024);
      GLDS16(w1l + gw, sm + 40960 + i*1024);
    }
    __syncthreads();
    #pragma unroll
    for (int ks = 0; ks < 2; ++ks){
      int ra = w*16 + lm;
      int offa = ra*128 + (((ks*4+quad) ^ (ra&7))*16);
      bf16x8 ah = *(const bf16x8*)(sm + offa);
      bf16x8 al = *(const bf16x8*)(sm + 8192 + offa);
      #pragma unroll
      for (int sub = 0; sub < 2; ++sub){
        #pragma unroll
        for (int n = 0; n < 4; ++n){
          int r = n*16 + lm;
          int off = r*128 + (((ks*4+quad) ^ (r&7))*16);
          bf16x8 bh = *(const bf16x8*)(sm + 16384 + sub*16384 + off);
          bf16x8 bl = *(const bf16x8*)(sm + 24576 + sub*16384 + off);
          acc[sub][n] = MFMA16(ah, bh, acc[sub][n]);
          acc[sub][n] = MFMA16(ah, bl, acc[sub][n]);
          acc[sub][n] = MFMA16(al, bh, acc[sub][n]);
        }
      }
    }
  }
  #pragma unroll
  for (int sub = 0; sub < 2; ++sub){
    int p = pg*2 + sub;
    if (p == 5){
      float* op = proj + (size_t)5*524288;
      #pragma unroll
      for (int n = 0; n < 4; ++n)
        #pragma unroll
        for (int e = 0; e < 4; ++e){
          int r = rb*64 + w*16 + quad*4 + e;
          op[(size_t)r*64 + n*16 + lm] = acc[sub][n][e];
        }
    } else {
      unsigned short* oph = projh + (size_t)p*524288;
      unsigned short* opl = projl + (size_t)p*524288;
      #pragma unroll
      for (int n = 0; n < 4; ++n)
        #pragma unroll
        for (int e = 0; e < 4; ++e){
          int r = rb*64 + w*16 + quad*4 + e;
          float f = acc[sub][n][e];
          short hs = f2bf(f);
          oph[(size_t)r*64 + n*16 + lm] = (unsigned short)hs;
          opl[(size_t)r*64 + n*16 + lm] = (unsigned short)f2bf(f - bf2f(hs));
        }
    }
  }
}

// ---------------- P1b: V_c f32 -> V_c^T fp16 (per batch 64 x 2048) ----------------
__global__ void k_vct(const float* __restrict__ proj, _Float16* __restrict__ vct){
  __shared__ float T[64][65];
  int b = blockIdx.y, st = blockIdx.x;       // s-tile [0,32)
  int tid = threadIdx.x;
  const float* vc = proj + 5*524288 + (size_t)b*131072;
  int sloc = tid >> 2, cp = (tid & 3)*16;
  #pragma unroll
  for (int j = 0; j < 4; ++j){
    f32x4 v = *(const f32x4*)(vc + (size_t)(st*64 + sloc)*64 + cp + j*4);
    #pragma unroll
    for (int e = 0; e < 4; ++e) T[sloc][cp + j*4 + e] = v[e];
  }
  __syncthreads();
  int d = tid >> 2, sp = (tid & 3)*16;
  f16x8 h0, h1;
  #pragma unroll
  for (int j = 0; j < 8; ++j) h0[j] = (_Float16)T[sp + j][d];
  #pragma unroll
  for (int j = 0; j < 8; ++j) h1[j] = (_Float16)T[sp + 8 + j][d];
  size_t o = (size_t)b*131072 + (size_t)d*2048 + st*64 + sp;
  *(f16x8*)(vct + o) = h0; *(f16x8*)(vct + o + 8) = h1;
}

// ---------------- P2: term1 / sigmoid-gate tiles, LDS-staged split GEMM -> fp16 ----------------
__global__ __launch_bounds__(256,2) void k_p2(
    const unsigned short* __restrict__ ph, const unsigned short* __restrict__ pl,
    _Float16* __restrict__ t1, _Float16* __restrict__ sg){
  __shared__ __align__(16) char sm[65536];
  int b = blockIdx.y;
  int t = blockIdx.x;                        // [0,272): 136 term1 + 136 sig tiles
  bool isSig = t >= 136;
  if (isSig) t -= 136;
  int a = 0, bb = 0;
  #pragma unroll 1
  for (int aa = 0; aa < 16; ++aa){
    int c = isSig ? (16 - aa) : (aa + 1);
    if (t < c){ a = aa; bb = isSig ? (aa + t) : t; break; }
    t -= c;
  }
  int pa = isSig ? 0 : 3;                    // A = Qu : Qc
  int pb = isSig ? 1 : 2;                    // B = Ku : Vu
  const char* Ahg = (const char*)ph + (size_t)pa*1048576;
  const char* Alg = (const char*)pl + (size_t)pa*1048576;
  const char* Bhg = (const char*)ph + (size_t)pb*1048576;
  const char* Blg = (const char*)pl + (size_t)pb*1048576;
  int tid = threadIdx.x, w = tid >> 6, lane = tid & 63;
  int lm = lane & 15, quad = lane >> 4;
  int srow = lane >> 3, scg = (lane & 7) ^ srow;
  int wm = (w & 1)*64, wn = (w >> 1)*64;
  #pragma unroll
  for (int i2 = 0; i2 < 4; ++i2){
    int i = w*4 + i2;
    int rl = i*8 + srow;
    size_t ga = (size_t)(b*2048 + a*128  + rl)*128 + scg*16;
    size_t gb = (size_t)(b*2048 + bb*128 + rl)*128 + scg*16;
    GLDS16(Ahg + ga, sm +         i*1024);
    GLDS16(Alg + ga, sm + 16384 + i*1024);
    GLDS16(Bhg + gb, sm + 32768 + i*1024);
    GLDS16(Blg + gb, sm + 49152 + i*1024);
  }
  __syncthreads();
  f32x4 acc[4][4] = {};
  #pragma unroll
  for (int ks = 0; ks < 2; ++ks){
    bf16x8 bh[4], bl[4];
    #pragma unroll
    for (int n = 0; n < 4; ++n){
      int r = wn + n*16 + lm;
      int off = r*128 + (((ks*4+quad) ^ (r&7))*16);
      bh[n] = *(const bf16x8*)(sm + 32768 + off);
      bl[n] = *(const bf16x8*)(sm + 49152 + off);
    }
    #pragma unroll
    for (int m = 0; m < 4; ++m){
      int r = wm + m*16 + lm;
      int off = r*128 + (((ks*4+quad) ^ (r&7))*16);
      bf16x8 ah = *(const bf16x8*)(sm + off);
      bf16x8 al = *(const bf16x8*)(sm + 16384 + off);
      #pragma unroll
      for (int n = 0; n < 4; ++n){
        acc[m][n] = MFMA16(ah, bh[n], acc[m][n]);
        acc[m][n] = MFMA16(ah, bl[n], acc[m][n]);
        acc[m][n] = MFMA16(al, bh[n], acc[m][n]);
      }
    }
  }
  __syncthreads();
  _Float16* Tt = (_Float16*)sm;              // 128x128 fp16 tile
  #pragma unroll
  for (int m = 0; m < 4; ++m){
    #pragma unroll
    for (int n = 0; n < 4; ++n){
      #pragma unroll
      for (int e = 0; e < 4; ++e){
        int il = wm + m*16 + quad*4 + e;
        int jl = wn + n*16 + lm;
        int gi = a*128 + il, gj = bb*128 + jl;
        float v = acc[m][n][e] * 0.125f;
        float outv;
        if (!isSig) outv = (gj <= gi) ? v : 0.0f;
        else        outv = (gj >  gi) ? (1.0f/(1.0f + __expf(-v))) : 0.0f;
        Tt[il*128 + jl] = (_Float16)outv;
      }
    }
  }
  __syncthreads();
  _Float16* outp = (isSig ? sg : t1) + (size_t)b*4194304;
  #pragma unroll
  for (int r = 0; r < 8; ++r){
    int lrow = w*32 + r*4 + (lane >> 4);
    int c16 = lane & 15;
    f32x4 vv = *(const f32x4*)(sm + lrow*256 + c16*16);
    *(f32x4*)((char*)(outp + (size_t)(a*128 + lrow)*2048 + bb*128) + c16*16) = vv;
  }
}

// ---------------- P3: S_u = term1 @ sig^T (fp16 MFMA, tri-tiled, DOUBLE-BUFFERED) + S_c ----------------
__global__ __launch_bounds__(256,2) void k_p3(
    const unsigned short* __restrict__ ph, const unsigned short* __restrict__ pl,
    const _Float16* __restrict__ t1, const _Float16* __restrict__ sg,
    _Float16* __restrict__ lg){
  __shared__ __align__(16) char sm[65536];   // buf0: A@0 B@16K | buf1: A@32K B@48K
  int b = blockIdx.y;
  int v = blockIdx.x, I = 0, K = 0;
  #pragma unroll 1
  for (int d = 15; d >= 0; --d){             // longest (I-K) first
    int nd = 16 - d;
    if (v < nd){ I = d + v; K = v; break; }
    v -= nd;
  }
  int tid = threadIdx.x, w = tid >> 6, lane = tid & 63;
  int lm = lane & 15, quad = lane >> 4;
  size_t mat = (size_t)b * 4194304;
  const char* Ag = (const char*)(t1 + mat);
  const char* Bg = (const char*)(sg + mat);
  int srow = lane >> 3, scg = (lane & 7) ^ srow;
  int wm = (w & 1)*64, wn = (w >> 1)*64;
  int nsteps = 2*(I - K) + 2;
  int j0 = 2*K;

  auto stage = [&](int j64, int base){
    size_t colb = (size_t)j64*128 + scg*16;
    #pragma unroll
    for (int i2 = 0; i2 < 4; ++i2){
      int i = w*4 + i2;
      int rl = i*8 + srow;
      GLDS16(Ag + (size_t)(I*128 + rl)*4096 + colb, sm + base +         i*1024);
      GLDS16(Bg + (size_t)(K*128 + rl)*4096 + colb, sm + base + 16384 + i*1024);
    }
  };

  f32x4 su[4][4] = {};
  stage(j0, 0);
  for (int step = 0; step < nsteps; ++step){
    int cur = (step & 1) << 15;
    __syncthreads();                          // drains cur's DMA
    if (step + 1 < nsteps) stage(j0 + step + 1, (~step & 1) << 15);  // prefetch overlaps compute
    #pragma unroll
    for (int ks = 0; ks < 2; ++ks){
      f16x8 bf[4];
      #pragma unroll
      for (int n = 0; n < 4; ++n){
        int r = wn + n*16 + lm;
        bf[n] = *(const f16x8*)(sm + cur + 16384 + r*128 + (((ks*4+quad) ^ (r&7))*16));
      }
      #pragma unroll
      for (int m = 0; m < 4; ++m){
        int r = wm + m*16 + lm;
        f16x8 af = *(const f16x8*)(sm + cur + r*128 + (((ks*4+quad) ^ (r&7))*16));
        #pragma unroll
        for (int n = 0; n < 4; ++n)
          su[m][n] = MFMAF16(af, bf[n], su[m][n]);
      }
    }
  }
  // fused S_c = Qc @ Kc^T (split bf16 from prebuilt h/l)
  const char* Qh = (const char*)ph + (size_t)3*1048576;
  const char* Ql = (const char*)pl + (size_t)3*1048576;
  const char* Kh = (const char*)ph + (size_t)4*1048576;
  const char* Kl = (const char*)pl + (size_t)4*1048576;
  f32x4 sc[4][4] = {};
  #pragma unroll
  for (int ks = 0; ks < 2; ++ks){
    bf16x8 kh[4], kl[4];
    #pragma unroll
    for (int n = 0; n < 4; ++n){
      size_t off = (size_t)(b*2048 + K*128 + wn + n*16 + lm)*128 + (ks*32 + quad*8)*2;
      kh[n] = *(const bf16x8*)(Kh + off);
      kl[n] = *(const bf16x8*)(Kl + off);
    }
    #pragma unroll
    for (int m = 0; m < 4; ++m){
      size_t off = (size_t)(b*2048 + I*128 + wm + m*16 + lm)*128 + (ks*32 + quad*8)*2;
      bf16x8 ah = *(const bf16x8*)(Qh + off);
      bf16x8 al = *(const bf16x8*)(Ql + off);
      #pragma unroll
      for (int n = 0; n < 4; ++n){
        sc[m][n] = MFMA16(ah, kh[n], sc[m][n]);
        sc[m][n] = MFMA16(ah, kl[n], sc[m][n]);
        sc[m][n] = MFMA16(al, kh[n], sc[m][n]);
      }
    }
  }
  __syncthreads();
  _Float16* Tt = (_Float16*)sm;              // 128x128 fp16 logits tile
  #pragma unroll
  for (int m = 0; m < 4; ++m){
    #pragma unroll
    for (int n = 0; n < 4; ++n){
      #pragma unroll
      for (int e = 0; e < 4; ++e){
        int il = wm + m*16 + quad*4 + e;
        int jl = wn + n*16 + lm;
        float xv = su[m][n][e];
        float sgm = 1.0f/(1.0f + __expf(-xv));
        Tt[il*128 + jl] = (_Float16)(sc[m][n][e]*0.125f - xv*sgm);
      }
    }
  }
  __syncthreads();
  _Float16* lgb = lg + mat;
  #pragma unroll
  for (int r = 0; r < 8; ++r){
    int lrow = w*32 + r*4 + (lane >> 4);
    int c16 = lane & 15;
    f32x4 vv = *(const f32x4*)(sm + lrow*256 + c16*16);
    *(f32x4*)((char*)(lgb + (size_t)(I*128 + lrow)*2048 + K*128) + c16*16) = vv;
  }
}

// ---------------- P4 (fused): band softmax + P @ V_c, whole 16x2048 band staged in LDS ----------------
__global__ __launch_bounds__(256,2) void k_p4(const _Float16* __restrict__ lg,
    const _Float16* __restrict__ vct, float* __restrict__ out){
  __shared__ __align__(16) char sm[66048];   // Ls 64K | Mz 256B | Sz 256B
  float* Mz = (float*)(sm + 65536);
  float* Sz = (float*)(sm + 65792);
  int b = blockIdx.y;
  int band = 127 - blockIdx.x;               // longest first
  int r0 = band*16;
  int tid = threadIdx.x, w = tid >> 6, lane = tid & 63;
  int lm = lane & 15, quad = lane >> 4;
  const char* lgb = (const char*)lg + ((size_t)b*4194304 + (size_t)r0*2048)*2;
  const _Float16* vb = vct + (size_t)b*131072;
  int nkt = ((r0 + 15) >> 6) + 1;
  int fc = (r0 + 1) >> 6;
  int srl = lane >> 3, ssl = lane & 7;
  // stage band (rows r0..r0+15, cols 0..nkt*64) with XOR slot swizzle
  for (int kt = w; kt < nkt; kt += 4){
    #pragma unroll
    for (int i2 = 0; i2 < 2; ++i2){
      int rl = i2*8 + srl;
      GLDS16(lgb + (size_t)rl*4096 + kt*128 + ((ssl ^ (rl & 7))*16),
             sm + kt*2048 + i2*1024);
    }
  }
  __syncthreads();
  // sweep 1: causal row max
  float m_r = -3.0e38f;
  for (int kt = w; kt < nkt; kt += 4){
    #pragma unroll
    for (int half = 0; half < 2; ++half){
      int sl = quad*2 + half;
      f16x8 v = *(const f16x8*)(sm + kt*2048 + lm*128 + ((sl ^ (lm & 7))*16));
      int cb = kt*64 + sl*8;
      #pragma unroll
      for (int e = 0; e < 8; ++e)
        m_r = (cb + e <= r0 + lm) ? fmaxf(m_r, (float)v[e]) : m_r;
    }
  }
  m_r = fmaxf(m_r, __shfl_xor(m_r, 16));
  m_r = fmaxf(m_r, __shfl_xor(m_r, 32));
  Mz[w*16 + lm] = m_r;
  __syncthreads();
  float mfin = fmaxf(fmaxf(Mz[lm], Mz[16 + lm]), fmaxf(Mz[32 + lm], Mz[48 + lm]));
  // sweep 2: sum of exp(x - mfin)
  float s_r = 0.0f;
  for (int kt = w; kt < nkt; kt += 4){
    #pragma unroll
    for (int half = 0; half < 2; ++half){
      int sl = quad*2 + half;
      f16x8 v = *(const f16x8*)(sm + kt*2048 + lm*128 + ((sl ^ (lm & 7))*16));
      int cb = kt*64 + sl*8;
      #pragma unroll
      for (int e = 0; e < 8; ++e)
        if (cb + e <= r0 + lm) s_r += __expf((float)v[e] - mfin);
    }
  }
  s_r += __shfl_xor(s_r, 16);
  s_r += __shfl_xor(s_r, 32);
  Sz[w*16 + lm] = s_r;
  // pass 2: MFMA P @ V^T, chunks striped across waves
  f32x4 acc[4] = {};
  for (int kt = w; kt < nkt; kt += 4){
    bool full = kt < fc;
    #pragma unroll
    for (int ks = 0; ks < 2; ++ks){
      f16x8 Lv = *(const f16x8*)(sm + kt*2048 + lm*128 + (((ks*4+quad) ^ (lm & 7))*16));
      int jbase = kt*64 + ks*32 + quad*8;
      f16x8 af;
      #pragma unroll
      for (int e = 0; e < 8; ++e){
        float p = __expf((float)Lv[e] - mfin);
        if (!full && (jbase + e > r0 + lm)) p = 0.0f;
        af[e] = (_Float16)p;
      }
      #pragma unroll
      for (int n = 0; n < 4; ++n){
        f16x8 bv = *(const f16x8*)(vb + (size_t)(n*16 + lm)*2048 + jbase);
        acc[n] = MFMAF16(af, bv, acc[n]);
      }
    }
  }
  __syncthreads();
  float* Ot = (float*)sm;                    // [4][16][64], reuses dead Ls
  #pragma unroll
  for (int n = 0; n < 4; ++n)
    #pragma unroll
    for (int e = 0; e < 4; ++e)
      Ot[(w*16 + quad*4 + e)*64 + n*16 + lm] = acc[n][e];
  __syncthreads();
  int row = tid >> 4, c4 = (tid & 15)*4;
  f32x4 s = *(const f32x4*)&Ot[row*64 + c4];
  #pragma unroll
  for (int ww = 1; ww < 4; ++ww){
    f32x4 t2 = *(const f32x4*)&Ot[(ww*16 + row)*64 + c4];
    s[0]+=t2[0]; s[1]+=t2[1]; s[2]+=t2[2]; s[3]+=t2[3];
  }
  float z = Sz[row] + Sz[16 + row] + Sz[32 + row] + Sz[48 + row];
  f32x4 o = { s[0]/z, s[1]/z, s[2]/z, s[3]/z };
  *(f32x4*)(out + ((size_t)b*2048 + r0 + row)*64 + c4) = o;
}

// ---------------- workspace layout (bytes) ----------------
static const size_t OFF_PROJ  = 0;           // 8192x64 f32 (p5 only used)
static const size_t OFF_WTH   = 12582912;    // 6 x 64x1024 bf16
static const size_t OFF_WTL   = 13369344;
static const size_t OFF_PROJH = 14155776;    // 6 x 8192x64 bf16
static const size_t OFF_PROJL = 20447232;
static const size_t OFF_VCT   = 26738688;    // 4 x 64x2048 f16
static const size_t OFF_T1    = 27787264;    // 4 x 2048^2 f16
static const size_t OFF_SG    = 61341696;
static const size_t OFF_LG    = 94896128;
static const size_t OFF_XH    = 128450560;   // 8192x1024 bf16
static const size_t OFF_XL    = 145227776;
// total = 162,004,992 bytes

extern "C" void kernel_launch(void* const* d_in, const int* in_sizes, int n_in,
                              void* d_out, int out_size, void* d_ws, size_t ws_size,
                              hipStream_t stream){
  (void)in_sizes; (void)n_in; (void)out_size; (void)ws_size;
  const float* x = (const float*)d_in[0];
  char* ws = (char*)d_ws;
  float*          proj  = (float*)(ws + OFF_PROJ);
  unsigned short* wth   = (unsigned short*)(ws + OFF_WTH);
  unsigned short* wtl   = (unsigned short*)(ws + OFF_WTL);
  unsigned short* projh = (unsigned short*)(ws + OFF_PROJH);
  unsigned short* projl = (unsigned short*)(ws + OFF_PROJL);
  _Float16*       vct   = (_Float16*)(ws + OFF_VCT);
  _Float16*       t1    = (_Float16*)(ws + OFF_T1);
  _Float16*       sg    = (_Float16*)(ws + OFF_SG);
  _Float16*       lg    = (_Float16*)(ws + OFF_LG);
  unsigned short* xh    = (unsigned short*)(ws + OFF_XH);
  unsigned short* xl    = (unsigned short*)(ws + OFF_XL);

  k_wt    <<<dim3(256,6),  256, 0, stream>>>((const float*)d_in[1], (const float*)d_in[2],
                                             (const float*)d_in[3], (const float*)d_in[4],
                                             (const float*)d_in[5], (const float*)d_in[6], wth, wtl);
  k_xsplit<<<dim3(4096),   256, 0, stream>>>(x, xh, xl);
  k_proj  <<<dim3(384),    256, 0, stream>>>(xh, xl, wth, wtl, proj, projh, projl);
  k_vct   <<<dim3(32,4),   256, 0, stream>>>(proj, vct);
  k_p2    <<<dim3(272,4),  256, 0, stream>>>(projh, projl, t1, sg);
  k_p3    <<<dim3(136,4),  256, 0, stream>>>(projh, projl, t1, sg, lg);
  k_p4    <<<dim3(128,4),  256, 0, stream>>>(lg, vct, (float*)d_out);
}

// Round 9
// 213.315 us; speedup vs baseline: 3.1203x; 1.0248x over previous
//
#include <hip/hip_runtime.h>
#include <hip/hip_bf16.h>

// B=4, S=2048, D=1024, DH=64. Inputs/outputs are FLOAT32 (per reference).
typedef short bf16x8 __attribute__((ext_vector_type(8)));
typedef float f32x4  __attribute__((ext_vector_type(4)));
typedef _Float16 f16x8 __attribute__((ext_vector_type(8)));

#define MFMA16(a,b,c)  __builtin_amdgcn_mfma_f32_16x16x32_bf16((a),(b),(c),0,0,0)
#define MFMAF16(a,b,c) __builtin_amdgcn_mfma_f32_16x16x32_f16((a),(b),(c),0,0,0)

// async global->LDS: 16B per lane, lane i lands at lds_base + i*16
#define GLDS16(g,l) __builtin_amdgcn_global_load_lds( \
    (const __attribute__((address_space(1))) void*)(g), \
    (__attribute__((address_space(3))) void*)(l), 16, 0, 0)

// p3 load-balanced bins: 136 tri-tiles LPT-packed into 64 bins (1 block/CU)
struct P3Bins { unsigned char cnt[64]; unsigned char tiles[64][14]; };

__device__ __forceinline__ short f2bf(float f){
  union { float f; unsigned u; } v; v.f = f;
  unsigned r = v.u + 0x7fffu + ((v.u >> 16) & 1u);
  return (short)(r >> 16);
}
__device__ __forceinline__ float bf2f(short h){
  union { unsigned u; float f; } v; v.u = ((unsigned)(unsigned short)h) << 16;
  return v.f;
}
__device__ __forceinline__ void split8v(f32x4 a, f32x4 b, bf16x8& h, bf16x8& l){
  float t[8] = {a[0],a[1],a[2],a[3],b[0],b[1],b[2],b[3]};
  #pragma unroll
  for (int e = 0; e < 8; ++e){
    short hs = f2bf(t[e]);
    h[e] = hs;
    l[e] = f2bf(t[e] - bf2f(hs));
  }
}

// ---------------- P0a: transpose+split 6 weights (1024x64 f32 -> 64x1024 bf16 hi/lo) ----------------
__global__ void k_wt(const float* w0, const float* w1, const float* w2,
                     const float* w3, const float* w4, const float* w5,
                     unsigned short* __restrict__ wth, unsigned short* __restrict__ wtl){
  int p = blockIdx.y;
  const float* wp = p==0?w0:p==1?w1:p==2?w2:p==3?w3:p==4?w4:w5;
  int idx = blockIdx.x*256 + threadIdx.x;     // [0,65536)
  int n = idx >> 10, k = idx & 1023;
  float v = wp[k*64 + n];
  short hs = f2bf(v);
  wth[(size_t)p*65536 + n*1024 + k] = (unsigned short)hs;
  wtl[(size_t)p*65536 + n*1024 + k] = (unsigned short)f2bf(v - bf2f(hs));
}

// ---------------- P0b: x f32 -> xh/xl bf16 (once) ----------------
__global__ void k_xsplit(const float* __restrict__ x,
                         unsigned short* __restrict__ xh, unsigned short* __restrict__ xl){
  size_t i = ((size_t)blockIdx.x*256 + threadIdx.x)*8;
  f32x4 a = *(const f32x4*)(x + i);
  f32x4 b = *(const f32x4*)(x + i + 4);
  bf16x8 h, l;
  split8v(a, b, h, l);
  *(bf16x8*)(xh + i) = h;
  *(bf16x8*)(xl + i) = l;
}

// ---------------- P1: projections, 2 p's per block, DMA-staged ----------------
__global__ __launch_bounds__(256) void k_proj(
    const unsigned short* __restrict__ xh, const unsigned short* __restrict__ xl,
    const unsigned short* __restrict__ wth, const unsigned short* __restrict__ wtl,
    float* __restrict__ proj,
    unsigned short* __restrict__ projh, unsigned short* __restrict__ projl){
  __shared__ __align__(16) char sm[49152];  // xh 8K | xl 8K | w0h 8K | w0l 8K | w1h 8K | w1l 8K
  int blk = blockIdx.x;
  int rb = blk/3, pg = blk - rb*3;
  int tid = threadIdx.x, w = tid >> 6, lane = tid & 63;
  int lm = lane & 15, quad = lane >> 4;
  int srow = lane >> 3, scg = (lane & 7) ^ srow;
  const char* xhg = (const char*)xh;
  const char* xlg = (const char*)xl;
  const char* w0h = (const char*)wth + (size_t)(pg*2  )*131072;
  const char* w0l = (const char*)wtl + (size_t)(pg*2  )*131072;
  const char* w1h = (const char*)wth + (size_t)(pg*2+1)*131072;
  const char* w1l = (const char*)wtl + (size_t)(pg*2+1)*131072;
  f32x4 acc[2][4] = {};
  for (int k0 = 0; k0 < 1024; k0 += 64){
    __syncthreads();
    size_t cb = (size_t)k0*2 + scg*16;
    #pragma unroll
    for (int i2 = 0; i2 < 2; ++i2){
      int i = w*2 + i2;
      size_t gx = (size_t)(rb*64 + i*8 + srow)*2048 + cb;
      size_t gw = (size_t)(i*8 + srow)*2048 + cb;
      GLDS16(xhg + gx, sm +         i*1024);
      GLDS16(xlg + gx, sm +  8192 + i*1024);
      GLDS16(w0h + gw, sm + 16384 + i*1024);
      GLDS16(w0l + gw, sm + 24576 + i*1024);
      GLDS16(w1h + gw, sm + 32768 + i*1024);
      GLDS16(w1l + gw, sm + 40960 + i*1024);
    }
    __syncthreads();
    #pragma unroll
    for (int ks = 0; ks < 2; ++ks){
      int ra = w*16 + lm;
      int offa = ra*128 + (((ks*4+quad) ^ (ra&7))*16);
      bf16x8 ah = *(const bf16x8*)(sm + offa);
      bf16x8 al = *(const bf16x8*)(sm + 8192 + offa);
      #pragma unroll
      for (int sub = 0; sub < 2; ++sub){
        #pragma unroll
        for (int n = 0; n < 4; ++n){
          int r = n*16 + lm;
          int off = r*128 + (((ks*4+quad) ^ (r&7))*16);
          bf16x8 bh = *(const bf16x8*)(sm + 16384 + sub*16384 + off);
          bf16x8 bl = *(const bf16x8*)(sm + 24576 + sub*16384 + off);
          acc[sub][n] = MFMA16(ah, bh, acc[sub][n]);
          acc[sub][n] = MFMA16(ah, bl, acc[sub][n]);
          acc[sub][n] = MFMA16(al, bh, acc[sub][n]);
        }
      }
    }
  }
  #pragma unroll
  for (int sub = 0; sub < 2; ++sub){
    int p = pg*2 + sub;
    if (p == 5){
      float* op = proj + (size_t)5*524288;
      #pragma unroll
      for (int n = 0; n < 4; ++n)
        #pragma unroll
        for (int e = 0; e < 4; ++e){
          int r = rb*64 + w*16 + quad*4 + e;
          op[(size_t)r*64 + n*16 + lm] = acc[sub][n][e];
        }
    } else {
      unsigned short* oph = projh + (size_t)p*524288;
      unsigned short* opl = projl + (size_t)p*524288;
      #pragma unroll
      for (int n = 0; n < 4; ++n)
        #pragma unroll
        for (int e = 0; e < 4; ++e){
          int r = rb*64 + w*16 + quad*4 + e;
          float f = acc[sub][n][e];
          short hs = f2bf(f);
          oph[(size_t)r*64 + n*16 + lm] = (unsigned short)hs;
          opl[(size_t)r*64 + n*16 + lm] = (unsigned short)f2bf(f - bf2f(hs));
        }
    }
  }
}

// ---------------- P1b: V_c f32 -> V_c^T fp16 (per batch 64 x 2048) ----------------
__global__ void k_vct(const float* __restrict__ proj, _Float16* __restrict__ vct){
  __shared__ float T[64][65];
  int b = blockIdx.y, st = blockIdx.x;       // s-tile [0,32)
  int tid = threadIdx.x;
  const float* vc = proj + 5*524288 + (size_t)b*131072;
  int sloc = tid >> 2, cp = (tid & 3)*16;
  #pragma unroll
  for (int j = 0; j < 4; ++j){
    f32x4 v = *(const f32x4*)(vc + (size_t)(st*64 + sloc)*64 + cp + j*4);
    #pragma unroll
    for (int e = 0; e < 4; ++e) T[sloc][cp + j*4 + e] = v[e];
  }
  __syncthreads();
  int d = tid >> 2, sp = (tid & 3)*16;
  f16x8 h0, h1;
  #pragma unroll
  for (int j = 0; j < 8; ++j) h0[j] = (_Float16)T[sp + j][d];
  #pragma unroll
  for (int j = 0; j < 8; ++j) h1[j] = (_Float16)T[sp + 8 + j][d];
  size_t o = (size_t)b*131072 + (size_t)d*2048 + st*64 + sp;
  *(f16x8*)(vct + o) = h0; *(f16x8*)(vct + o + 8) = h1;
}

// ---------------- P2: term1 / sigmoid-gate tiles, LDS-staged split GEMM -> fp16 ----------------
__global__ __launch_bounds__(256,2) void k_p2(
    const unsigned short* __restrict__ ph, const unsigned short* __restrict__ pl,
    _Float16* __restrict__ t1, _Float16* __restrict__ sg){
  __shared__ __align__(16) char sm[65536];
  int b = blockIdx.y;
  int t = blockIdx.x;                        // [0,272): 136 term1 + 136 sig tiles
  bool isSig = t >= 136;
  if (isSig) t -= 136;
  int a = 0, bb = 0;
  #pragma unroll 1
  for (int aa = 0; aa < 16; ++aa){
    int c = isSig ? (16 - aa) : (aa + 1);
    if (t < c){ a = aa; bb = isSig ? (aa + t) : t; break; }
    t -= c;
  }
  int pa = isSig ? 0 : 3;                    // A = Qu : Qc
  int pb = isSig ? 1 : 2;                    // B = Ku : Vu
  const char* Ahg = (const char*)ph + (size_t)pa*1048576;
  const char* Alg = (const char*)pl + (size_t)pa*1048576;
  const char* Bhg = (const char*)ph + (size_t)pb*1048576;
  const char* Blg = (const char*)pl + (size_t)pb*1048576;
  int tid = threadIdx.x, w = tid >> 6, lane = tid & 63;
  int lm = lane & 15, quad = lane >> 4;
  int srow = lane >> 3, scg = (lane & 7) ^ srow;
  int wm = (w & 1)*64, wn = (w >> 1)*64;
  #pragma unroll
  for (int i2 = 0; i2 < 4; ++i2){
    int i = w*4 + i2;
    int rl = i*8 + srow;
    size_t ga = (size_t)(b*2048 + a*128  + rl)*128 + scg*16;
    size_t gb = (size_t)(b*2048 + bb*128 + rl)*128 + scg*16;
    GLDS16(Ahg + ga, sm +         i*1024);
    GLDS16(Alg + ga, sm + 16384 + i*1024);
    GLDS16(Bhg + gb, sm + 32768 + i*1024);
    GLDS16(Blg + gb, sm + 49152 + i*1024);
  }
  __syncthreads();
  f32x4 acc[4][4] = {};
  #pragma unroll
  for (int ks = 0; ks < 2; ++ks){
    bf16x8 bh[4], bl[4];
    #pragma unroll
    for (int n = 0; n < 4; ++n){
      int r = wn + n*16 + lm;
      int off = r*128 + (((ks*4+quad) ^ (r&7))*16);
      bh[n] = *(const bf16x8*)(sm + 32768 + off);
      bl[n] = *(const bf16x8*)(sm + 49152 + off);
    }
    #pragma unroll
    for (int m = 0; m < 4; ++m){
      int r = wm + m*16 + lm;
      int off = r*128 + (((ks*4+quad) ^ (r&7))*16);
      bf16x8 ah = *(const bf16x8*)(sm + off);
      bf16x8 al = *(const bf16x8*)(sm + 16384 + off);
      #pragma unroll
      for (int n = 0; n < 4; ++n){
        acc[m][n] = MFMA16(ah, bh[n], acc[m][n]);
        acc[m][n] = MFMA16(ah, bl[n], acc[m][n]);
        acc[m][n] = MFMA16(al, bh[n], acc[m][n]);
      }
    }
  }
  __syncthreads();
  _Float16* Tt = (_Float16*)sm;              // 128x128 fp16 tile
  #pragma unroll
  for (int m = 0; m < 4; ++m){
    #pragma unroll
    for (int n = 0; n < 4; ++n){
      #pragma unroll
      for (int e = 0; e < 4; ++e){
        int il = wm + m*16 + quad*4 + e;
        int jl = wn + n*16 + lm;
        int gi = a*128 + il, gj = bb*128 + jl;
        float v = acc[m][n][e] * 0.125f;
        float outv;
        if (!isSig) outv = (gj <= gi) ? v : 0.0f;
        else        outv = (gj >  gi) ? (1.0f/(1.0f + __expf(-v))) : 0.0f;
        Tt[il*128 + jl] = (_Float16)outv;
      }
    }
  }
  __syncthreads();
  _Float16* outp = (isSig ? sg : t1) + (size_t)b*4194304;
  #pragma unroll
  for (int r = 0; r < 8; ++r){
    int lrow = w*32 + r*4 + (lane >> 4);
    int c16 = lane & 15;
    f32x4 vv = *(const f32x4*)(sm + lrow*256 + c16*16);
    *(f32x4*)((char*)(outp + (size_t)(a*128 + lrow)*2048 + bb*128) + c16*16) = vv;
  }
}

// ---------------- P3: S_u (fp16 MFMA, dbuf) + S_c, LPT-balanced bins (1 block/CU) ----------------
__global__ __launch_bounds__(256,2) void k_p3(
    const unsigned short* __restrict__ ph, const unsigned short* __restrict__ pl,
    const _Float16* __restrict__ t1, const _Float16* __restrict__ sg,
    _Float16* __restrict__ lg, P3Bins bz){
  __shared__ __align__(16) char sm[65536];   // buf0: A@0 B@16K | buf1: A@32K B@48K
  int bin = blockIdx.x;
  int b = blockIdx.y;
  int tid = threadIdx.x, w = tid >> 6, lane = tid & 63;
  int lm = lane & 15, quad = lane >> 4;
  size_t mat = (size_t)b * 4194304;
  const char* Ag = (const char*)(t1 + mat);
  const char* Bg = (const char*)(sg + mat);
  int srow = lane >> 3, scg = (lane & 7) ^ srow;
  int wm = (w & 1)*64, wn = (w >> 1)*64;
  int ntiles = bz.cnt[bin];

  for (int tix = 0; tix < ntiles; ++tix){
    int tv = bz.tiles[bin][tix];
    int I = tv >> 4, K = tv & 15;
    int nsteps = 2*(I - K) + 2;
    int j0 = 2*K;
    __syncthreads();                          // protect LDS vs previous tile's epilogue reads

    auto stage = [&](int j64, int base){
      size_t colb = (size_t)j64*128 + scg*16;
      #pragma unroll
      for (int i2 = 0; i2 < 4; ++i2){
        int i = w*4 + i2;
        int rl = i*8 + srow;
        GLDS16(Ag + (size_t)(I*128 + rl)*4096 + colb, sm + base +         i*1024);
        GLDS16(Bg + (size_t)(K*128 + rl)*4096 + colb, sm + base + 16384 + i*1024);
      }
    };

    f32x4 su[4][4] = {};
    stage(j0, 0);
    for (int step = 0; step < nsteps; ++step){
      int cur = (step & 1) << 15;
      __syncthreads();                        // drains cur's DMA
      if (step + 1 < nsteps) stage(j0 + step + 1, (~step & 1) << 15);
      #pragma unroll
      for (int ks = 0; ks < 2; ++ks){
        f16x8 bf[4];
        #pragma unroll
        for (int n = 0; n < 4; ++n){
          int r = wn + n*16 + lm;
          bf[n] = *(const f16x8*)(sm + cur + 16384 + r*128 + (((ks*4+quad) ^ (r&7))*16));
        }
        #pragma unroll
        for (int m = 0; m < 4; ++m){
          int r = wm + m*16 + lm;
          f16x8 af = *(const f16x8*)(sm + cur + r*128 + (((ks*4+quad) ^ (r&7))*16));
          #pragma unroll
          for (int n = 0; n < 4; ++n)
            su[m][n] = MFMAF16(af, bf[n], su[m][n]);
        }
      }
    }
    // fused S_c = Qc @ Kc^T (split bf16 from prebuilt h/l)
    const char* Qh = (const char*)ph + (size_t)3*1048576;
    const char* Ql = (const char*)pl + (size_t)3*1048576;
    const char* Kh = (const char*)ph + (size_t)4*1048576;
    const char* Kl = (const char*)pl + (size_t)4*1048576;
    f32x4 sc[4][4] = {};
    #pragma unroll
    for (int ks = 0; ks < 2; ++ks){
      bf16x8 kh[4], kl[4];
      #pragma unroll
      for (int n = 0; n < 4; ++n){
        size_t off = (size_t)(b*2048 + K*128 + wn + n*16 + lm)*128 + (ks*32 + quad*8)*2;
        kh[n] = *(const bf16x8*)(Kh + off);
        kl[n] = *(const bf16x8*)(Kl + off);
      }
      #pragma unroll
      for (int m = 0; m < 4; ++m){
        size_t off = (size_t)(b*2048 + I*128 + wm + m*16 + lm)*128 + (ks*32 + quad*8)*2;
        bf16x8 ah = *(const bf16x8*)(Qh + off);
        bf16x8 al = *(const bf16x8*)(Ql + off);
        #pragma unroll
        for (int n = 0; n < 4; ++n){
          sc[m][n] = MFMA16(ah, kh[n], sc[m][n]);
          sc[m][n] = MFMA16(ah, kl[n], sc[m][n]);
          sc[m][n] = MFMA16(al, kh[n], sc[m][n]);
        }
      }
    }
    __syncthreads();
    _Float16* Tt = (_Float16*)sm;            // 128x128 fp16 logits tile
    #pragma unroll
    for (int m = 0; m < 4; ++m){
      #pragma unroll
      for (int n = 0; n < 4; ++n){
        #pragma unroll
        for (int e = 0; e < 4; ++e){
          int il = wm + m*16 + quad*4 + e;
          int jl = wn + n*16 + lm;
          float xv = su[m][n][e];
          float sgm = 1.0f/(1.0f + __expf(-xv));
          Tt[il*128 + jl] = (_Float16)(sc[m][n][e]*0.125f - xv*sgm);
        }
      }
    }
    __syncthreads();
    _Float16* lgb = lg + mat;
    #pragma unroll
    for (int r = 0; r < 8; ++r){
      int lrow = w*32 + r*4 + (lane >> 4);
      int c16 = lane & 15;
      f32x4 vv = *(const f32x4*)(sm + lrow*256 + c16*16);
      *(f32x4*)((char*)(lgb + (size_t)(I*128 + lrow)*2048 + K*128) + c16*16) = vv;
    }
  }
}

// ---------------- P4 (fused): band softmax + P @ V_c, paired bands for balance ----------------
__global__ __launch_bounds__(256,2) void k_p4(const _Float16* __restrict__ lg,
    const _Float16* __restrict__ vct, float* __restrict__ out){
  __shared__ __align__(16) char sm[66048];   // Ls 64K | Mz 256B | Sz 256B
  float* Mz = (float*)(sm + 65536);
  float* Sz = (float*)(sm + 65792);
  int b = blockIdx.y;
  int b1 = blockIdx.x;                       // 0..63; handles bands b1 and 127-b1
  int tid = threadIdx.x, w = tid >> 6, lane = tid & 63;
  int lm = lane & 15, quad = lane >> 4;
  const _Float16* vb = vct + (size_t)b*131072;
  for (int pass = 0; pass < 2; ++pass){
    int band = pass ? (127 - b1) : b1;
    int r0 = band*16;
    const char* lgb = (const char*)lg + ((size_t)b*4194304 + (size_t)r0*2048)*2;
    int nkt = ((r0 + 15) >> 6) + 1;
    int fc = (r0 + 1) >> 6;
    int srl = lane >> 3, ssl = lane & 7;
    __syncthreads();                          // LDS reuse vs previous pass
    for (int kt = w; kt < nkt; kt += 4){
      #pragma unroll
      for (int i2 = 0; i2 < 2; ++i2){
        int rl = i2*8 + srl;
        GLDS16(lgb + (size_t)rl*4096 + kt*128 + ((ssl ^ (rl & 7))*16),
               sm + kt*2048 + i2*1024);
      }
    }
    __syncthreads();
    // sweep 1: causal row max
    float m_r = -3.0e38f;
    for (int kt = w; kt < nkt; kt += 4){
      #pragma unroll
      for (int half = 0; half < 2; ++half){
        int sl = quad*2 + half;
        f16x8 v = *(const f16x8*)(sm + kt*2048 + lm*128 + ((sl ^ (lm & 7))*16));
        int cb = kt*64 + sl*8;
        #pragma unroll
        for (int e = 0; e < 8; ++e)
          m_r = (cb + e <= r0 + lm) ? fmaxf(m_r, (float)v[e]) : m_r;
      }
    }
    m_r = fmaxf(m_r, __shfl_xor(m_r, 16));
    m_r = fmaxf(m_r, __shfl_xor(m_r, 32));
    Mz[w*16 + lm] = m_r;
    __syncthreads();
    float mfin = fmaxf(fmaxf(Mz[lm], Mz[16 + lm]), fmaxf(Mz[32 + lm], Mz[48 + lm]));
    // sweep 2: sum of exp(x - mfin)
    float s_r = 0.0f;
    for (int kt = w; kt < nkt; kt += 4){
      #pragma unroll
      for (int half = 0; half < 2; ++half){
        int sl = quad*2 + half;
        f16x8 v = *(const f16x8*)(sm + kt*2048 + lm*128 + ((sl ^ (lm & 7))*16));
        int cb = kt*64 + sl*8;
        #pragma unroll
        for (int e = 0; e < 8; ++e)
          if (cb + e <= r0 + lm) s_r += __expf((float)v[e] - mfin);
      }
    }
    s_r += __shfl_xor(s_r, 16);
    s_r += __shfl_xor(s_r, 32);
    Sz[w*16 + lm] = s_r;
    // MFMA P @ V^T, chunks striped across waves
    f32x4 acc[4] = {};
    for (int kt = w; kt < nkt; kt += 4){
      bool full = kt < fc;
      #pragma unroll
      for (int ks = 0; ks < 2; ++ks){
        f16x8 Lv = *(const f16x8*)(sm + kt*2048 + lm*128 + (((ks*4+quad) ^ (lm & 7))*16));
        int jbase = kt*64 + ks*32 + quad*8;
        f16x8 af;
        #pragma unroll
        for (int e = 0; e < 8; ++e){
          float p = __expf((float)Lv[e] - mfin);
          if (!full && (jbase + e > r0 + lm)) p = 0.0f;
          af[e] = (_Float16)p;
        }
        #pragma unroll
        for (int n = 0; n < 4; ++n){
          f16x8 bv = *(const f16x8*)(vb + (size_t)(n*16 + lm)*2048 + jbase);
          acc[n] = MFMAF16(af, bv, acc[n]);
        }
      }
    }
    __syncthreads();
    float* Ot = (float*)sm;                  // [4][16][64], reuses dead Ls
    #pragma unroll
    for (int n = 0; n < 4; ++n)
      #pragma unroll
      for (int e = 0; e < 4; ++e)
        Ot[(w*16 + quad*4 + e)*64 + n*16 + lm] = acc[n][e];
    __syncthreads();
    int row = tid >> 4, c4 = (tid & 15)*4;
    f32x4 s = *(const f32x4*)&Ot[row*64 + c4];
    #pragma unroll
    for (int ww = 1; ww < 4; ++ww){
      f32x4 t2 = *(const f32x4*)&Ot[(ww*16 + row)*64 + c4];
      s[0]+=t2[0]; s[1]+=t2[1]; s[2]+=t2[2]; s[3]+=t2[3];
    }
    float z = Sz[row] + Sz[16 + row] + Sz[32 + row] + Sz[48 + row];
    f32x4 o = { s[0]/z, s[1]/z, s[2]/z, s[3]/z };
    *(f32x4*)(out + ((size_t)b*2048 + r0 + row)*64 + c4) = o;
  }
}

// ---------------- workspace layout (bytes) ----------------
static const size_t OFF_PROJ  = 0;           // 8192x64 f32 (p5 only used)
static const size_t OFF_WTH   = 12582912;    // 6 x 64x1024 bf16
static const size_t OFF_WTL   = 13369344;
static const size_t OFF_PROJH = 14155776;    // 6 x 8192x64 bf16
static const size_t OFF_PROJL = 20447232;
static const size_t OFF_VCT   = 26738688;    // 4 x 64x2048 f16
static const size_t OFF_T1    = 27787264;    // 4 x 2048^2 f16
static const size_t OFF_SG    = 61341696;
static const size_t OFF_LG    = 94896128;
static const size_t OFF_XH    = 128450560;   // 8192x1024 bf16
static const size_t OFF_XL    = 145227776;
// total = 162,004,992 bytes

static P3Bins build_bins(){
  P3Bins bz;
  int load[64];
  for (int i = 0; i < 64; ++i){ bz.cnt[i] = 0; load[i] = 0; }
  // tiles in descending length (len = 2*(I-K)+2); LPT into 64 bins
  for (int d = 15; d >= 0; --d){
    for (int K = 0; K + d < 16; ++K){
      int I = K + d;
      int len = 2*d + 2;
      int best = 0;
      for (int bin = 1; bin < 64; ++bin) if (load[bin] < load[best]) best = bin;
      load[best] += len;
      bz.tiles[best][bz.cnt[best]++] = (unsigned char)(I*16 + K);
    }
  }
  return bz;
}

extern "C" void kernel_launch(void* const* d_in, const int* in_sizes, int n_in,
                              void* d_out, int out_size, void* d_ws, size_t ws_size,
                              hipStream_t stream){
  (void)in_sizes; (void)n_in; (void)out_size; (void)ws_size;
  const float* x = (const float*)d_in[0];
  char* ws = (char*)d_ws;
  float*          proj  = (float*)(ws + OFF_PROJ);
  unsigned short* wth   = (unsigned short*)(ws + OFF_WTH);
  unsigned short* wtl   = (unsigned short*)(ws + OFF_WTL);
  unsigned short* projh = (unsigned short*)(ws + OFF_PROJH);
  unsigned short* projl = (unsigned short*)(ws + OFF_PROJL);
  _Float16*       vct   = (_Float16*)(ws + OFF_VCT);
  _Float16*       t1    = (_Float16*)(ws + OFF_T1);
  _Float16*       sg    = (_Float16*)(ws + OFF_SG);
  _Float16*       lg    = (_Float16*)(ws + OFF_LG);
  unsigned short* xh    = (unsigned short*)(ws + OFF_XH);
  unsigned short* xl    = (unsigned short*)(ws + OFF_XL);

  P3Bins bz = build_bins();                  // deterministic, recomputed every call

  k_wt    <<<dim3(256,6),  256, 0, stream>>>((const float*)d_in[1], (const float*)d_in[2],
                                             (const float*)d_in[3], (const float*)d_in[4],
                                             (const float*)d_in[5], (const float*)d_in[6], wth, wtl);
  k_xsplit<<<dim3(4096),   256, 0, stream>>>(x, xh, xl);
  k_proj  <<<dim3(384),    256, 0, stream>>>(xh, xl, wth, wtl, proj, projh, projl);
  k_vct   <<<dim3(32,4),   256, 0, stream>>>(proj, vct);
  k_p2    <<<dim3(272,4),  256, 0, stream>>>(projh, projl, t1, sg);
  k_p3    <<<dim3(64,4),   256, 0, stream>>>(projh, projl, t1, sg, lg, bz);
  k_p4    <<<dim3(64,4),   256, 0, stream>>>(lg, vct, (float*)d_out);
}